// Round 1
// baseline (58715.826 us; speedup 1.0000x reference)
//
#include <hip/hip_runtime.h>
#include <cstdint>
#include <cstddef>

#define THREADS 256
#define CK 16

// Direct 3x3 SAME conv, NCHW/OIHW, fused bias+relu (+optional spatial mask).
// Tile: 64 couts x (8 rows x 16 cols) pixels per block, 256 threads.
// Each thread: 8 couts x 4 pixels = 32 accumulators.
__global__ __launch_bounds__(256, 2)
void conv3x3_kernel(const float* __restrict__ in, const float* __restrict__ w,
                    const float* __restrict__ bias, const int* __restrict__ msk,
                    float* __restrict__ out,
                    int Cin, int Cout, int H, int W, int coutTot, int useMask)
{
    __shared__ float lds_in[CK][10][20];   // [ci][row][col] rows y0-1..y0+8, cols x0-1..x0+16
    __shared__ float lds_w[CK][9][64];     // [ci][tap][co]

    const int tid = threadIdx.x;
    const int co_lane = tid & 7;           // 8 groups of couts
    const int pix_lane = tid >> 3;         // 0..31
    const int prow = pix_lane >> 2;        // 0..7
    const int pcol = (pix_lane & 3) << 2;  // 0,4,8,12

    const int n = blockIdx.z;
    const int co0 = blockIdx.y << 6;
    const int tpr = W >> 4;                // tiles per row (power of 2)
    const int tx = blockIdx.x & (tpr - 1);
    const int ty = blockIdx.x / tpr;
    const int x0 = tx << 4;
    const int y0 = ty << 3;

    const int HW = H * W;
    const float* in_n = in + (size_t)n * Cin * HW;

    float acc[8][4];
#pragma unroll
    for (int j = 0; j < 8; ++j)
#pragma unroll
        for (int q = 0; q < 4; ++q) acc[j][q] = 0.f;

    for (int ci0 = 0; ci0 < Cin; ci0 += CK) {
        __syncthreads();
        // stage input tile: CK x 10 x 18 (zero-fill OOB / ci >= Cin)
        for (int idx = tid; idx < CK * 10 * 18; idx += THREADS) {
            int ci = idx / 180;
            int rem = idx - ci * 180;
            int r = rem / 18;
            int c = rem - r * 18;
            int y = y0 + r - 1;
            int x = x0 + c - 1;
            float v = 0.f;
            if ((ci0 + ci) < Cin && y >= 0 && y < H && x >= 0 && x < W)
                v = in_n[(size_t)(ci0 + ci) * HW + y * W + x];
            lds_in[ci][r][c] = v;
        }
        // stage weights: per co, CK*9 floats are contiguous in [co][ci][tap]
        for (int idx = tid; idx < 64 * CK * 9; idx += THREADS) {
            int co = idx / (CK * 9);
            int rem = idx - co * (CK * 9);
            int ci = rem / 9;
            int tap = rem - ci * 9;
            float v = 0.f;
            if ((ci0 + ci) < Cin)
                v = w[((size_t)(co0 + co) * Cin + (ci0 + ci)) * 9 + tap];
            lds_w[ci][tap][co] = v;
        }
        __syncthreads();

#pragma unroll 1
        for (int ci = 0; ci < CK; ++ci) {
            float iv[3][6];
#pragma unroll
            for (int r = 0; r < 3; ++r)
#pragma unroll
                for (int c = 0; c < 6; ++c)
                    iv[r][c] = lds_in[ci][prow + r][pcol + c];
#pragma unroll
            for (int dy = 0; dy < 3; ++dy)
#pragma unroll
                for (int dx = 0; dx < 3; ++dx) {
                    float wv[8];
#pragma unroll
                    for (int j = 0; j < 8; ++j)
                        wv[j] = lds_w[ci][dy * 3 + dx][(co_lane << 3) + j];
#pragma unroll
                    for (int j = 0; j < 8; ++j)
#pragma unroll
                        for (int q = 0; q < 4; ++q)
                            acc[j][q] = fmaf(wv[j], iv[dy][dx + q], acc[j][q]);
                }
        }
    }

    const int y = y0 + prow;
    const int x = x0 + pcol;
    float m[4] = {1.f, 1.f, 1.f, 1.f};
    if (useMask) {
#pragma unroll
        for (int q = 0; q < 4; ++q)
            m[q] = (msk[(size_t)n * HW + (size_t)y * W + x + q] > 0) ? 1.f : 0.f;
    }
    float* out_n = out + (size_t)n * coutTot * HW;
#pragma unroll
    for (int j = 0; j < 8; ++j) {
        int co = co0 + (co_lane << 3) + j;
        float b = bias[co];
        float4 v;
        v.x = fmaxf(acc[j][0] + b, 0.f) * m[0];
        v.y = fmaxf(acc[j][1] + b, 0.f) * m[1];
        v.z = fmaxf(acc[j][2] + b, 0.f) * m[2];
        v.w = fmaxf(acc[j][3] + b, 0.f) * m[3];
        *reinterpret_cast<float4*>(out_n + (size_t)co * HW + (size_t)y * W + x) = v;
    }
}

// Bilinear 2x upsample (align_corners=False => clamped 0.75/0.25 taps).
// in: [4][256][Hin][Win]; out: [4][outChTot][2Hin][2Win] ch 0..255; add or write.
__global__ __launch_bounds__(256, 4)
void up2_kernel(const float* __restrict__ in, float* __restrict__ out,
                int Hin, int Win, int outChTot, int add)
{
    const int C = 256;
    const int Hout = Hin << 1, Wout = Win << 1;
    const int wsh = __ffs(Wout) - 1;
    const int hsh = __ffs(Hout) - 1;
    size_t total = (size_t)4 * C * Hout * Wout;
    for (size_t i = (size_t)blockIdx.x * THREADS + threadIdx.x; i < total;
         i += (size_t)gridDim.x * THREADS) {
        int x = (int)(i & (Wout - 1));
        size_t r = i >> wsh;
        int y = (int)(r & (Hout - 1));
        r >>= hsh;
        int c = (int)(r & (C - 1));
        int n = (int)(r >> 8);
        int iy = y >> 1, ix = x >> 1;
        int y2 = (y & 1) ? min(iy + 1, Hin - 1) : max(iy - 1, 0);
        int x2 = (x & 1) ? min(ix + 1, Win - 1) : max(ix - 1, 0);
        const float* p = in + (size_t)(n * C + c) * Hin * Win;
        float v00 = p[iy * Win + ix];
        float v01 = p[iy * Win + x2];
        float v10 = p[y2 * Win + ix];
        float v11 = p[y2 * Win + x2];
        float v = 0.5625f * v00 + 0.1875f * (v01 + v10) + 0.0625f * v11;
        size_t o = (((size_t)n * outChTot + c) * Hout + y) * Wout + x;
        if (add) out[o] += v;
        else out[o] = v;
    }
}

// Copy rel/abs coords into channels 256..259 of the 260-channel concat buffer.
__global__ void coords_kernel(const float* __restrict__ rel, const float* __restrict__ abs_,
                              float* __restrict__ Xc)
{
    size_t i = (size_t)blockIdx.x * THREADS + threadIdx.x;
    const size_t total = 4ull * 4 * 128 * 128;
    if (i >= total) return;
    int x = (int)(i & 127);
    size_t r = i >> 7;
    int y = (int)(r & 127);
    r >>= 7;
    int c = (int)(r & 3);
    int n = (int)(r >> 2);
    const float* src = (c < 2) ? rel : abs_;
    int cc = c & 1;
    float v = src[(((size_t)n * 2 + cc) * 128 + y) * 128 + x];
    Xc[(((size_t)n * 260 + 256 + c) * 128 + y) * 128 + x] = v;
}

// 1x1 conv predictor: [4][512][128][128] -> [4][75][128][128], bias, no relu.
__global__ __launch_bounds__(256, 2)
void pred_kernel(const float* __restrict__ in, const float* __restrict__ w,
                 const float* __restrict__ bias, float* __restrict__ out)
{
    __shared__ float lw[25 * 512];
    const int co0 = blockIdx.y * 25;
    for (int idx = threadIdx.x; idx < 25 * 512; idx += THREADS)
        lw[idx] = w[(size_t)(co0 + idx / 512) * 512 + (idx & 511)];
    __syncthreads();
    size_t pix = (size_t)blockIdx.x * THREADS + threadIdx.x;  // over 4*128*128
    int x = (int)(pix & 127);
    size_t r = pix >> 7;
    int y = (int)(r & 127);
    int n = (int)(r >> 7);
    const float* ip = in + (size_t)n * 512 * 16384 + (size_t)y * 128 + x;
    float acc[25];
#pragma unroll
    for (int j = 0; j < 25; ++j) acc[j] = bias[co0 + j];
    for (int ci = 0; ci < 512; ci += 4) {
        float v0 = ip[(size_t)(ci + 0) * 16384];
        float v1 = ip[(size_t)(ci + 1) * 16384];
        float v2 = ip[(size_t)(ci + 2) * 16384];
        float v3 = ip[(size_t)(ci + 3) * 16384];
#pragma unroll
        for (int j = 0; j < 25; ++j) {
            float4 wv = *reinterpret_cast<const float4*>(&lw[j * 512 + ci]);
            acc[j] = fmaf(wv.x, v0, acc[j]);
            acc[j] = fmaf(wv.y, v1, acc[j]);
            acc[j] = fmaf(wv.z, v2, acc[j]);
            acc[j] = fmaf(wv.w, v3, acc[j]);
        }
    }
    float* op = out + (size_t)n * 75 * 16384 + (size_t)y * 128 + x;
#pragma unroll
    for (int j = 0; j < 25; ++j)
        op[(size_t)(co0 + j) * 16384] = acc[j];
}

extern "C" void kernel_launch(void* const* d_in, const int* in_sizes, int n_in,
                              void* d_out, int out_size, void* d_ws, size_t ws_size,
                              hipStream_t stream)
{
    const float* p2   = (const float*)d_in[0];
    const float* p3   = (const float*)d_in[1];
    const float* p4   = (const float*)d_in[2];
    const float* p5   = (const float*)d_in[3];
    const float* rel  = (const float*)d_in[4];
    const float* abs_ = (const float*)d_in[5];
    const int*   fg   = (const int*)d_in[6];
    const float* w_p2_0 = (const float*)d_in[7];
    const float* b_p2_0 = (const float*)d_in[8];
    const float* w_p3_0 = (const float*)d_in[9];
    const float* b_p3_0 = (const float*)d_in[10];
    const float* w_p4_0 = (const float*)d_in[11];
    const float* b_p4_0 = (const float*)d_in[12];
    const float* w_p4_1 = (const float*)d_in[13];
    const float* b_p4_1 = (const float*)d_in[14];
    const float* w_p5_0 = (const float*)d_in[15];
    const float* b_p5_0 = (const float*)d_in[16];
    const float* w_p5_1 = (const float*)d_in[17];
    const float* b_p5_1 = (const float*)d_in[18];
    const float* w_p5_2 = (const float*)d_in[19];
    const float* b_p5_2 = (const float*)d_in[20];
    const float* comb_w = (const float*)d_in[21];
    const float* comb_b = (const float*)d_in[22];
    const float* head_w0 = (const float*)d_in[23];
    const float* head_b0 = (const float*)d_in[24];
    const float* head_w  = (const float*)d_in[25];
    const float* head_b  = (const float*)d_in[26];
    const float* pred_w  = (const float*)d_in[27];
    const float* pred_b  = (const float*)d_in[28];

    // Workspace layout (floats), 256 MB total, with liveness-verified overlap:
    //   region0 [0, 33.5M):  Ha (512ch@128^2).  Xc (260ch@128^2, 17.0M) aliases it
    //                        during the scale/comb phase (dead before head0 writes Ha).
    //   region1 [33.5M, 67.1M): Hb. h (=comb out, 16.8M) aliases Hb[0:], written
    //                        after all temps die; temps alias Hb[0:10.8M] in scale phase.
    float* ws = (float*)d_ws;
    float* Ha   = ws;
    float* Hb   = ws + 33554432;
    float* Xc   = Ha;
    float* hbuf = Hb;
    float* t64a = Hb;
    float* t64b = Hb + 4194304;
    float* t32a = Hb + 8388608;
    float* t32b = Hb + 9437184;
    float* t16  = Hb + 10485760;

    auto conv = [&](const float* in, const float* wt, const float* bs,
                    float* out, int Cin, int Cout, int H, int W, int coutTot, int useMask) {
        dim3 grid((H >> 3) * (W >> 4), Cout >> 6, 4);
        conv3x3_kernel<<<grid, dim3(THREADS), 0, stream>>>(
            in, wt, bs, fg, out, Cin, Cout, H, W, coutTot, useMask);
    };
    auto up2 = [&](const float* in, float* out, int Hin, int Win, int outChTot, int add) {
        size_t total = 4ull * 256 * 4 * Hin * Win;
        int blocks = (int)((total + THREADS - 1) / THREADS);
        if (blocks > 4096) blocks = 4096;
        up2_kernel<<<dim3(blocks), dim3(THREADS), 0, stream>>>(in, out, Hin, Win, outChTot, add);
    };

    // ---- scale heads into Xc (260-channel concat buffer) ----
    coords_kernel<<<dim3(1024), dim3(THREADS), 0, stream>>>(rel, abs_, Xc);
    conv(p2, w_p2_0, b_p2_0, Xc, 256, 256, 128, 128, 260, 0);

    conv(p3, w_p3_0, b_p3_0, t64a, 256, 256, 64, 64, 256, 0);
    up2(t64a, Xc, 64, 64, 260, 1);

    conv(p4, w_p4_0, b_p4_0, t32a, 256, 256, 32, 32, 256, 0);
    up2(t32a, t64a, 32, 32, 256, 0);
    conv(t64a, w_p4_1, b_p4_1, t64b, 256, 256, 64, 64, 256, 0);
    up2(t64b, Xc, 64, 64, 260, 1);

    conv(p5, w_p5_0, b_p5_0, t16, 256, 256, 16, 16, 256, 0);
    up2(t16, t32a, 16, 16, 256, 0);
    conv(t32a, w_p5_1, b_p5_1, t32b, 256, 256, 32, 32, 256, 0);
    up2(t32b, t64a, 32, 32, 256, 0);
    conv(t64a, w_p5_2, b_p5_2, t64b, 256, 256, 64, 64, 256, 0);
    up2(t64b, Xc, 64, 64, 260, 1);

    // ---- comb conv (260 -> 256), relu + mask ----
    conv(Xc, comb_w, comb_b, hbuf, 260, 256, 128, 128, 256, 1);

    // ---- sparse head: 8 masked 3x3 convs ----
    conv(hbuf, head_w0, head_b0, Ha, 256, 512, 128, 128, 512, 1);
    float* src = Ha;
    float* dst = Hb;
    for (int i = 0; i < 7; ++i) {
        conv(src, head_w + (size_t)i * 512 * 512 * 9, head_b + (size_t)i * 512,
             dst, 512, 512, 128, 128, 512, 1);
        float* tmp = src; src = dst; dst = tmp;
    }

    // ---- predictor 1x1 ----
    pred_kernel<<<dim3(256, 3), dim3(THREADS), 0, stream>>>(src, pred_w, pred_b, (float*)d_out);
}

// Round 2
// 9529.799 us; speedup vs baseline: 6.1613x; 6.1613x over previous
//
#include <hip/hip_runtime.h>
#include <cstdint>
#include <cstddef>

#define THREADS 256

typedef short bf16x8 __attribute__((ext_vector_type(8)));
typedef float f32x4 __attribute__((ext_vector_type(4)));

__device__ __forceinline__ unsigned short f2bf(float f) {
    unsigned x = __float_as_uint(f);
    return (unsigned short)((x + 0x7FFFu + ((x >> 16) & 1u)) >> 16);
}

// ---------------------------------------------------------------------------
// Weight pack: fp32 OIHW -> [tap][cc][plane(hi,lo)][u(4)][co][8 bf16]
// (frag-ordered so A-fragments are coalesced global loads; zero-fill ci>=Cin)
// ---------------------------------------------------------------------------
__global__ void pack_w_kernel(const float* __restrict__ w, short* __restrict__ wp,
                              int Cin, int Cout, int CC)
{
    int idx = blockIdx.x * THREADS + threadIdx.x;
    int total = Cout * CC * 4;
    if (idx >= total) return;
    int u = idx & 3;
    int cc = (idx >> 2) % CC;
    int co = (idx >> 2) / CC;
    int ci0 = cc * 32 + u * 8;
    for (int tap = 0; tap < 9; ++tap) {
        bf16x8 hv, lv;
#pragma unroll
        for (int j = 0; j < 8; ++j) {
            int ci = ci0 + j;
            float v = (ci < Cin) ? w[((size_t)co * Cin + ci) * 9 + tap] : 0.f;
            unsigned short h = f2bf(v);
            float fh = __uint_as_float((unsigned)h << 16);
            unsigned short l = f2bf(v - fh);
            hv[j] = (short)h;
            lv[j] = (short)l;
        }
        size_t bh = ((((size_t)tap * CC + cc) * 2 + 0) * 4 + u) * Cout + co;
        size_t bl = ((((size_t)tap * CC + cc) * 2 + 1) * 4 + u) * Cout + co;
        *reinterpret_cast<bf16x8*>(wp + bh * 8) = hv;
        *reinterpret_cast<bf16x8*>(wp + bl * 8) = lv;
    }
}

// ---------------------------------------------------------------------------
// Implicit-GEMM 3x3 SAME conv, split-bf16 MFMA (16x16x32), bias+relu(+mask).
// Block: 128 couts x (8 rows x 16 cols). 4 waves, each 64co x 64px.
// A (weights) read direct from global (packed layout); B (acts) staged in LDS
// with XOR-swizzled 16B units (bank-balanced).
// ---------------------------------------------------------------------------
__global__ __launch_bounds__(256, 2)
void conv_mfma_kernel(const float* __restrict__ in, const short* __restrict__ wp,
                      const float* __restrict__ bias, const int* __restrict__ msk,
                      float* __restrict__ out,
                      int Cin, int CC, int Cout, int H, int W,
                      long long inNS, long long outNS, int useMask)
{
    __shared__ short Xl[2 * 180 * 32];   // [plane][item(row*18+col)][32 ci] bf16

    const int tid = threadIdx.x;
    const int lane = tid & 63;
    const int wave = tid >> 6;
    const int lm = lane & 15;            // A row / B col / C col
    const int lu = lane >> 4;            // k-unit (8 ci per unit)
    const int waveco = (wave & 1) * 64;  // wave co offset within 128
    const int wrow = (wave >> 1) * 4;    // wave row offset within 8

    const int n = blockIdx.z;
    const int co0 = blockIdx.y * 128;
    const int tpr = W >> 4;
    const int tx = blockIdx.x % tpr;
    const int ty = blockIdx.x / tpr;
    const int x0 = tx << 4;
    const int y0 = ty << 3;
    const int HW = H * W;
    const float* in_n = in + (size_t)n * inNS;

    f32x4 acc[4][4];
#pragma unroll
    for (int m = 0; m < 4; ++m)
#pragma unroll
        for (int nf = 0; nf < 4; ++nf)
            acc[m][nf] = (f32x4){0.f, 0.f, 0.f, 0.f};

    const size_t aLaneOff = ((size_t)lu * Cout + co0 + waveco + lm) * 8;
    const size_t pStride = (size_t)4 * Cout * 8;  // hi->lo plane stride (shorts)

    for (int cc = 0; cc < CC; ++cc) {
        __syncthreads();
        // ---- stage X tile (10x18 halo x 32 ci) as hi/lo bf16, swizzled ----
        for (int widx = tid; widx < 720; widx += THREADS) {
            int item = widx >> 2;
            int u = widx & 3;
            int row = item / 18;
            int col = item - row * 18;
            int y = y0 + row - 1;
            int x = x0 + col - 1;
            bool inb = (y >= 0) && (y < H) && (x >= 0) && (x < W);
            int cibase = cc * 32 + u * 8;
            const float* sp = in_n + (size_t)cibase * HW + (size_t)y * W + x;
            bf16x8 hv, lv;
#pragma unroll
            for (int j = 0; j < 8; ++j) {
                float v = 0.f;
                if (inb && (cibase + j) < Cin) v = sp[(size_t)j * HW];
                unsigned short h = f2bf(v);
                float fh = __uint_as_float((unsigned)h << 16);
                unsigned short l = f2bf(v - fh);
                hv[j] = (short)h;
                lv[j] = (short)l;
            }
            int off = (item * 4 + (u ^ ((item >> 1) & 3))) * 8;
            *reinterpret_cast<bf16x8*>(&Xl[off]) = hv;
            *reinterpret_cast<bf16x8*>(&Xl[5760 + off]) = lv;
        }
        __syncthreads();

#pragma unroll
        for (int tap = 0; tap < 9; ++tap) {
            const int dy = tap / 3;
            const int dx = tap - dy * 3;
            // A fragments (global, L2-hot)
            size_t abase = (((size_t)tap * CC + cc) * 2) * pStride;
            bf16x8 ah[4], al[4];
#pragma unroll
            for (int m = 0; m < 4; ++m) {
                ah[m] = *reinterpret_cast<const bf16x8*>(wp + abase + aLaneOff + (size_t)m * 128);
                al[m] = *reinterpret_cast<const bf16x8*>(wp + abase + pStride + aLaneOff + (size_t)m * 128);
            }
            // B fragments (LDS, swizzled)
            bf16x8 bh[4], bl[4];
#pragma unroll
            for (int nf = 0; nf < 4; ++nf) {
                int item = (wrow + nf + dy) * 18 + lm + dx;
                int off = (item * 4 + (lu ^ ((item >> 1) & 3))) * 8;
                bh[nf] = *reinterpret_cast<const bf16x8*>(&Xl[off]);
                bl[nf] = *reinterpret_cast<const bf16x8*>(&Xl[5760 + off]);
            }
#pragma unroll
            for (int m = 0; m < 4; ++m)
#pragma unroll
                for (int nf = 0; nf < 4; ++nf) {
                    acc[m][nf] = __builtin_amdgcn_mfma_f32_16x16x32_bf16(al[m], bh[nf], acc[m][nf], 0, 0, 0);
                    acc[m][nf] = __builtin_amdgcn_mfma_f32_16x16x32_bf16(ah[m], bl[nf], acc[m][nf], 0, 0, 0);
                    acc[m][nf] = __builtin_amdgcn_mfma_f32_16x16x32_bf16(ah[m], bh[nf], acc[m][nf], 0, 0, 0);
                }
        }
    }

    // ---- epilogue: bias + relu (+mask), fp32 NCHW store ----
    float* out_n = out + (size_t)n * outNS;
#pragma unroll
    for (int nf = 0; nf < 4; ++nf) {
        int y = y0 + wrow + nf;
        int x = x0 + lm;
        float mv = 1.f;
        if (useMask) mv = (msk[(size_t)n * HW + (size_t)y * W + x] > 0) ? 1.f : 0.f;
#pragma unroll
        for (int m = 0; m < 4; ++m) {
            f32x4 v = acc[m][nf];
#pragma unroll
            for (int r = 0; r < 4; ++r) {
                int co = co0 + waveco + m * 16 + lu * 4 + r;
                out_n[(size_t)co * HW + (size_t)y * W + x] = fmaxf(v[r] + bias[co], 0.f) * mv;
            }
        }
    }
}

// ---------------------------------------------------------------------------
// fp32 direct conv (round-1 kernel) -- kept for the small 16^2/32^2 convs.
// ---------------------------------------------------------------------------
#define CK 16
__global__ __launch_bounds__(256, 2)
void conv3x3_kernel(const float* __restrict__ in, const float* __restrict__ w,
                    const float* __restrict__ bias, const int* __restrict__ msk,
                    float* __restrict__ out,
                    int Cin, int Cout, int H, int W, int coutTot, int useMask)
{
    __shared__ float lds_in[CK][10][20];
    __shared__ float lds_w[CK][9][64];

    const int tid = threadIdx.x;
    const int co_lane = tid & 7;
    const int pix_lane = tid >> 3;
    const int prow = pix_lane >> 2;
    const int pcol = (pix_lane & 3) << 2;

    const int n = blockIdx.z;
    const int co0 = blockIdx.y << 6;
    const int tpr = W >> 4;
    const int tx = blockIdx.x & (tpr - 1);
    const int ty = blockIdx.x / tpr;
    const int x0 = tx << 4;
    const int y0 = ty << 3;

    const int HW = H * W;
    const float* in_n = in + (size_t)n * Cin * HW;

    float acc[8][4];
#pragma unroll
    for (int j = 0; j < 8; ++j)
#pragma unroll
        for (int q = 0; q < 4; ++q) acc[j][q] = 0.f;

    for (int ci0 = 0; ci0 < Cin; ci0 += CK) {
        __syncthreads();
        for (int idx = tid; idx < CK * 10 * 18; idx += THREADS) {
            int ci = idx / 180;
            int rem = idx - ci * 180;
            int r = rem / 18;
            int c = rem - r * 18;
            int y = y0 + r - 1;
            int x = x0 + c - 1;
            float v = 0.f;
            if ((ci0 + ci) < Cin && y >= 0 && y < H && x >= 0 && x < W)
                v = in_n[(size_t)(ci0 + ci) * HW + y * W + x];
            lds_in[ci][r][c] = v;
        }
        for (int idx = tid; idx < 64 * CK * 9; idx += THREADS) {
            int co = idx / (CK * 9);
            int rem = idx - co * (CK * 9);
            int ci = rem / 9;
            int tap = rem - ci * 9;
            float v = 0.f;
            if ((ci0 + ci) < Cin)
                v = w[((size_t)(co0 + co) * Cin + (ci0 + ci)) * 9 + tap];
            lds_w[ci][tap][co] = v;
        }
        __syncthreads();

#pragma unroll 1
        for (int ci = 0; ci < CK; ++ci) {
            float iv[3][6];
#pragma unroll
            for (int r = 0; r < 3; ++r)
#pragma unroll
                for (int c = 0; c < 6; ++c)
                    iv[r][c] = lds_in[ci][prow + r][pcol + c];
#pragma unroll
            for (int dy = 0; dy < 3; ++dy)
#pragma unroll
                for (int dx = 0; dx < 3; ++dx) {
                    float wv[8];
#pragma unroll
                    for (int j = 0; j < 8; ++j)
                        wv[j] = lds_w[ci][dy * 3 + dx][(co_lane << 3) + j];
#pragma unroll
                    for (int j = 0; j < 8; ++j)
#pragma unroll
                        for (int q = 0; q < 4; ++q)
                            acc[j][q] = fmaf(wv[j], iv[dy][dx + q], acc[j][q]);
                }
        }
    }

    const int y = y0 + prow;
    const int x = x0 + pcol;
    float m[4] = {1.f, 1.f, 1.f, 1.f};
    if (useMask) {
#pragma unroll
        for (int q = 0; q < 4; ++q)
            m[q] = (msk[(size_t)n * HW + (size_t)y * W + x + q] > 0) ? 1.f : 0.f;
    }
    float* out_n = out + (size_t)n * coutTot * HW;
#pragma unroll
    for (int j = 0; j < 8; ++j) {
        int co = co0 + (co_lane << 3) + j;
        float b = bias[co];
        float4 v;
        v.x = fmaxf(acc[j][0] + b, 0.f) * m[0];
        v.y = fmaxf(acc[j][1] + b, 0.f) * m[1];
        v.z = fmaxf(acc[j][2] + b, 0.f) * m[2];
        v.w = fmaxf(acc[j][3] + b, 0.f) * m[3];
        *reinterpret_cast<float4*>(out_n + (size_t)co * HW + (size_t)y * W + x) = v;
    }
}

// Bilinear 2x upsample (align_corners=False => clamped 0.75/0.25 taps).
__global__ __launch_bounds__(256, 4)
void up2_kernel(const float* __restrict__ in, float* __restrict__ out,
                int Hin, int Win, int outChTot, int add)
{
    const int C = 256;
    const int Hout = Hin << 1, Wout = Win << 1;
    const int wsh = __ffs(Wout) - 1;
    const int hsh = __ffs(Hout) - 1;
    size_t total = (size_t)4 * C * Hout * Wout;
    for (size_t i = (size_t)blockIdx.x * THREADS + threadIdx.x; i < total;
         i += (size_t)gridDim.x * THREADS) {
        int x = (int)(i & (Wout - 1));
        size_t r = i >> wsh;
        int y = (int)(r & (Hout - 1));
        r >>= hsh;
        int c = (int)(r & (C - 1));
        int n = (int)(r >> 8);
        int iy = y >> 1, ix = x >> 1;
        int y2 = (y & 1) ? min(iy + 1, Hin - 1) : max(iy - 1, 0);
        int x2 = (x & 1) ? min(ix + 1, Win - 1) : max(ix - 1, 0);
        const float* p = in + (size_t)(n * C + c) * Hin * Win;
        float v00 = p[iy * Win + ix];
        float v01 = p[iy * Win + x2];
        float v10 = p[y2 * Win + ix];
        float v11 = p[y2 * Win + x2];
        float v = 0.5625f * v00 + 0.1875f * (v01 + v10) + 0.0625f * v11;
        size_t o = (((size_t)n * outChTot + c) * Hout + y) * Wout + x;
        if (add) out[o] += v;
        else out[o] = v;
    }
}

__global__ void coords_kernel(const float* __restrict__ rel, const float* __restrict__ abs_,
                              float* __restrict__ Xc)
{
    size_t i = (size_t)blockIdx.x * THREADS + threadIdx.x;
    const size_t total = 4ull * 4 * 128 * 128;
    if (i >= total) return;
    int x = (int)(i & 127);
    size_t r = i >> 7;
    int y = (int)(r & 127);
    r >>= 7;
    int c = (int)(r & 3);
    int n = (int)(r >> 2);
    const float* src = (c < 2) ? rel : abs_;
    int cc = c & 1;
    float v = src[(((size_t)n * 2 + cc) * 128 + y) * 128 + x];
    Xc[(((size_t)n * 260 + 256 + c) * 128 + y) * 128 + x] = v;
}

// 1x1 conv predictor, single image: [512][128][128] -> [75][128][128].
__global__ __launch_bounds__(256, 2)
void pred_kernel(const float* __restrict__ in, const float* __restrict__ w,
                 const float* __restrict__ bias, float* __restrict__ out)
{
    __shared__ float lw[25 * 512];
    const int co0 = blockIdx.y * 25;
    for (int idx = threadIdx.x; idx < 25 * 512; idx += THREADS)
        lw[idx] = w[(size_t)(co0 + idx / 512) * 512 + (idx & 511)];
    __syncthreads();
    int pix = blockIdx.x * THREADS + threadIdx.x;  // 0..16383
    int x = pix & 127;
    int y = pix >> 7;
    const float* ip = in + (size_t)y * 128 + x;
    float acc[25];
#pragma unroll
    for (int j = 0; j < 25; ++j) acc[j] = bias[co0 + j];
    for (int ci = 0; ci < 512; ci += 4) {
        float v0 = ip[(size_t)(ci + 0) * 16384];
        float v1 = ip[(size_t)(ci + 1) * 16384];
        float v2 = ip[(size_t)(ci + 2) * 16384];
        float v3 = ip[(size_t)(ci + 3) * 16384];
#pragma unroll
        for (int j = 0; j < 25; ++j) {
            float4 wv = *reinterpret_cast<const float4*>(&lw[j * 512 + ci]);
            acc[j] = fmaf(wv.x, v0, acc[j]);
            acc[j] = fmaf(wv.y, v1, acc[j]);
            acc[j] = fmaf(wv.z, v2, acc[j]);
            acc[j] = fmaf(wv.w, v3, acc[j]);
        }
    }
    float* op = out + (size_t)y * 128 + x;
#pragma unroll
    for (int j = 0; j < 25; ++j)
        op[(size_t)(co0 + j) * 16384] = acc[j];
}

extern "C" void kernel_launch(void* const* d_in, const int* in_sizes, int n_in,
                              void* d_out, int out_size, void* d_ws, size_t ws_size,
                              hipStream_t stream)
{
    const float* p2   = (const float*)d_in[0];
    const float* p3   = (const float*)d_in[1];
    const float* p4   = (const float*)d_in[2];
    const float* p5   = (const float*)d_in[3];
    const float* rel  = (const float*)d_in[4];
    const float* abs_ = (const float*)d_in[5];
    const int*   fg   = (const int*)d_in[6];
    const float* w_p2_0 = (const float*)d_in[7];
    const float* b_p2_0 = (const float*)d_in[8];
    const float* w_p3_0 = (const float*)d_in[9];
    const float* b_p3_0 = (const float*)d_in[10];
    const float* w_p4_0 = (const float*)d_in[11];
    const float* b_p4_0 = (const float*)d_in[12];
    const float* w_p4_1 = (const float*)d_in[13];
    const float* b_p4_1 = (const float*)d_in[14];
    const float* w_p5_0 = (const float*)d_in[15];
    const float* b_p5_0 = (const float*)d_in[16];
    const float* w_p5_1 = (const float*)d_in[17];
    const float* b_p5_1 = (const float*)d_in[18];
    const float* w_p5_2 = (const float*)d_in[19];
    const float* b_p5_2 = (const float*)d_in[20];
    const float* comb_w = (const float*)d_in[21];
    const float* comb_b = (const float*)d_in[22];
    const float* head_w0 = (const float*)d_in[23];
    const float* head_b0 = (const float*)d_in[24];
    const float* head_w  = (const float*)d_in[25];
    const float* head_b  = (const float*)d_in[26];
    const float* pred_w  = (const float*)d_in[27];
    const float* pred_b  = (const float*)d_in[28];

    // Workspace layout (floats). Total 61,341,696 floats = 245.4 MB.
    //   Xc    [0,          17,039,360)  4n x 260ch @128^2; reused after comb for head1..7 packed W
    //   hbuf  [17,039,360, 33,816,576)  4n x 256ch @128^2 (comb output)
    //   pingA [33,816,576, 42,205,184)  1n x 512ch; also transient pack slot during scale phase
    //   pingB [42,205,184, 50,593,792)
    //   temps [50,593,792, 61,341,696)  scale-phase temps; reused for head0 packed W
    float* ws = (float*)d_ws;
    float* Xc    = ws;
    float* hbuf  = ws + 17039360;
    float* pingA = ws + 33816576;
    float* pingB = ws + 42205184;
    float* t64a  = ws + 50593792;
    float* t64b  = t64a + 4194304;
    float* t32a  = t64b + 4194304;
    float* t32b  = t32a + 1048576;
    float* t16   = t32b + 1048576;
    short* slotT   = (short*)pingA;   // transient packed W (<=2.7MB), dead before head0 writes pingA
    short* wpHead0 = (short*)t64a;    // 2,359,296 shorts; temps dead after scale phase
    short* wpHead  = (short*)Xc;      // 7 x 4,718,592 shorts = 16.5M floats <= 17.04M; Xc dead after comb

    auto packw = [&](const float* w, short* dst, int Cin, int Cout) {
        int CCl = (Cin + 31) / 32;
        int total = Cout * CCl * 4;
        pack_w_kernel<<<dim3((total + THREADS - 1) / THREADS), dim3(THREADS), 0, stream>>>(
            w, dst, Cin, Cout, CCl);
    };
    auto convm = [&](const float* in, const short* wpk, const float* bs, float* outp,
                     int Cin, int Cout, int H, int W, long long inNS, long long outNS,
                     int nz, const int* mptr, int useMask) {
        int CCl = (Cin + 31) / 32;
        dim3 grid((W / 16) * (H / 8), Cout / 128, nz);
        conv_mfma_kernel<<<grid, dim3(THREADS), 0, stream>>>(
            in, wpk, bs, mptr, outp, Cin, CCl, Cout, H, W, inNS, outNS, useMask);
    };
    auto conv_old = [&](const float* in, const float* wt, const float* bs,
                        float* out, int Cin, int Cout, int H, int W, int coutTot) {
        dim3 grid((H >> 3) * (W >> 4), Cout >> 6, 4);
        conv3x3_kernel<<<grid, dim3(THREADS), 0, stream>>>(
            in, wt, bs, fg, out, Cin, Cout, H, W, coutTot, 0);
    };
    auto up2 = [&](const float* in, float* out, int Hin, int Win, int outChTot, int add) {
        size_t total = 4ull * 256 * 4 * Hin * Win;
        int blocks = (int)((total + THREADS - 1) / THREADS);
        if (blocks > 4096) blocks = 4096;
        up2_kernel<<<dim3(blocks), dim3(THREADS), 0, stream>>>(in, out, Hin, Win, outChTot, add);
    };

    // ---- scale heads into Xc (260-channel concat buffer) ----
    packw(w_p2_0, slotT, 256, 256);
    convm(p2, slotT, b_p2_0, Xc, 256, 256, 128, 128, 256LL * 16384, 260LL * 16384, 4, nullptr, 0);
    coords_kernel<<<dim3(1024), dim3(THREADS), 0, stream>>>(rel, abs_, Xc);

    packw(w_p3_0, slotT, 256, 256);
    convm(p3, slotT, b_p3_0, t64a, 256, 256, 64, 64, 256LL * 4096, 256LL * 4096, 4, nullptr, 0);
    up2(t64a, Xc, 64, 64, 260, 1);

    conv_old(p4, w_p4_0, b_p4_0, t32a, 256, 256, 32, 32, 256);
    up2(t32a, t64a, 32, 32, 256, 0);
    packw(w_p4_1, slotT, 256, 256);
    convm(t64a, slotT, b_p4_1, t64b, 256, 256, 64, 64, 256LL * 4096, 256LL * 4096, 4, nullptr, 0);
    up2(t64b, Xc, 64, 64, 260, 1);

    conv_old(p5, w_p5_0, b_p5_0, t16, 256, 256, 16, 16, 256);
    up2(t16, t32a, 16, 16, 256, 0);
    conv_old(t32a, w_p5_1, b_p5_1, t32b, 256, 256, 32, 32, 256);
    up2(t32b, t64a, 32, 32, 256, 0);
    packw(w_p5_2, slotT, 256, 256);
    convm(t64a, slotT, b_p5_2, t64b, 256, 256, 64, 64, 256LL * 4096, 256LL * 4096, 4, nullptr, 0);
    up2(t64b, Xc, 64, 64, 260, 1);

    // ---- comb conv (260 -> 256), relu + mask ----
    packw(comb_w, slotT, 260, 256);
    convm(Xc, slotT, comb_b, hbuf, 260, 256, 128, 128, 260LL * 16384, 256LL * 16384, 4, fg, 1);

    // ---- pack head weights (Xc + temps now dead) ----
    packw(head_w0, wpHead0, 256, 512);
    for (int i = 0; i < 7; ++i)
        packw(head_w + (size_t)i * 512 * 512 * 9, wpHead + (size_t)i * 4718592, 512, 512);

    // ---- per-image: 8 masked head convs + predictor ----
    for (int nn = 0; nn < 4; ++nn) {
        const float* src0 = hbuf + (size_t)nn * 256 * 16384;
        const int* mptr = fg + (size_t)nn * 16384;
        convm(src0, wpHead0, head_b0, pingA, 256, 512, 128, 128, 0, 0, 1, mptr, 1);
        float* s = pingA;
        float* d = pingB;
        for (int i = 0; i < 7; ++i) {
            convm(s, wpHead + (size_t)i * 4718592, head_b + (size_t)i * 512,
                  d, 512, 512, 128, 128, 0, 0, 1, mptr, 1);
            float* tmp = s; s = d; d = tmp;
        }
        pred_kernel<<<dim3(64, 3), dim3(THREADS), 0, stream>>>(
            s, pred_w, pred_b, (float*)d_out + (size_t)nn * 75 * 16384);
    }
}

// Round 3
// 5002.489 us; speedup vs baseline: 11.7373x; 1.9050x over previous
//
#include <hip/hip_runtime.h>
#include <cstdint>
#include <cstddef>

#define THREADS 256

typedef _Float16 f16x8 __attribute__((ext_vector_type(8)));
typedef _Float16 f16x4 __attribute__((ext_vector_type(4)));
typedef float f32x4 __attribute__((ext_vector_type(4)));

// ---------------------------------------------------------------------------
// Weight pack: fp32 OIHW -> fp16 [tap][cc][u(4)][co][8]  (zero-fill ci>=Cin)
// ---------------------------------------------------------------------------
__global__ void pack_w16_kernel(const float* __restrict__ w, _Float16* __restrict__ wp,
                                int Cin, int Cout, int CC)
{
    int idx = blockIdx.x * THREADS + threadIdx.x;
    int total = Cout * CC * 4;
    if (idx >= total) return;
    int u = idx & 3;
    int cc = (idx >> 2) % CC;
    int co = (idx >> 2) / CC;
    int ci0 = cc * 32 + u * 8;
    for (int tap = 0; tap < 9; ++tap) {
        f16x8 v;
#pragma unroll
        for (int j = 0; j < 8; ++j) {
            int ci = ci0 + j;
            v[j] = (ci < Cin) ? (_Float16)w[((size_t)co * Cin + ci) * 9 + tap] : (_Float16)0.f;
        }
        *reinterpret_cast<f16x8*>(wp + ((((size_t)tap * CC + cc) * 4 + u) * Cout + co) * 8) = v;
    }
}

// ---------------------------------------------------------------------------
// fp32-NCHW-input implicit-GEMM 3x3 conv, fp16 MFMA. Block 128co x (8x16)px,
// 256 thr. OUTMODE 0: fp32 NCHW (+opt mask). OUTMODE 1: NHWC fp16 + mask.
// ---------------------------------------------------------------------------
template<int OUTMODE>
__global__ __launch_bounds__(256, 2)
void conv_f32_kernel(const float* __restrict__ in, const _Float16* __restrict__ wp,
                     const float* __restrict__ bias, const int* __restrict__ msk,
                     void* __restrict__ outp, int Cin, int CC, int Cout,
                     int H, int W, int coutTot, int useMask)
{
    __shared__ _Float16 Xs[720 * 8];   // [item(10x18)][u(4)][8]
    const int tid = threadIdx.x;
    const int lane = tid & 63;
    const int wave = tid >> 6;
    const int lm = lane & 15;
    const int lu = lane >> 4;
    const int waveco = (wave & 1) * 64;
    const int wrow = (wave >> 1) * 4;
    const int n = blockIdx.z;
    const int co0 = blockIdx.y * 128;
    const int tpr = W >> 4;
    const int tx = blockIdx.x % tpr;
    const int ty = blockIdx.x / tpr;
    const int x0 = tx << 4;
    const int y0 = ty << 3;
    const int HW = H * W;
    const float* in_n = in + (size_t)n * Cin * HW;

    f32x4 acc[4][4];
#pragma unroll
    for (int m = 0; m < 4; ++m)
#pragma unroll
        for (int nf = 0; nf < 4; ++nf)
            acc[m][nf] = (f32x4){0.f, 0.f, 0.f, 0.f};

    const size_t tstride = (size_t)CC * 4 * Cout * 8;
    for (int cc = 0; cc < CC; ++cc) {
        __syncthreads();
        for (int s = tid; s < 720; s += THREADS) {
            int item = s >> 2, u = s & 3;
            int row = item / 18;
            int col = item - row * 18;
            int y = y0 + row - 1, x = x0 + col - 1;
            bool inb = (y >= 0) && (y < H) && (x >= 0) && (x < W);
            int cibase = cc * 32 + u * 8;
            const float* sp = in_n + (size_t)cibase * HW + (size_t)y * W + x;
            f16x8 v;
#pragma unroll
            for (int j = 0; j < 8; ++j) {
                float f = (inb && (cibase + j) < Cin) ? sp[(size_t)j * HW] : 0.f;
                v[j] = (_Float16)f;
            }
            *reinterpret_cast<f16x8*>(&Xs[s * 8]) = v;
        }
        __syncthreads();
        const _Float16* wb = wp + (((size_t)cc * 4 + lu) * Cout + co0 + waveco + lm) * 8;
#pragma unroll
        for (int tap = 0; tap < 9; ++tap) {
            const int dy = tap / 3, dx = tap % 3;
            const _Float16* wt = wb + (size_t)tap * tstride;
            f16x8 a[4], b[4];
#pragma unroll
            for (int m = 0; m < 4; ++m)
                a[m] = *reinterpret_cast<const f16x8*>(wt + m * 128);
#pragma unroll
            for (int nf = 0; nf < 4; ++nf)
                b[nf] = *reinterpret_cast<const f16x8*>(
                    &Xs[(((wrow + nf + dy) * 18 + lm + dx) * 4 + lu) * 8]);
#pragma unroll
            for (int m = 0; m < 4; ++m)
#pragma unroll
                for (int nf = 0; nf < 4; ++nf)
                    acc[m][nf] = __builtin_amdgcn_mfma_f32_16x16x32_f16(a[m], b[nf], acc[m][nf], 0, 0, 0);
        }
    }

    const int xE = x0 + lm;
#pragma unroll
    for (int nf = 0; nf < 4; ++nf) {
        const int y = y0 + wrow + nf;
        float mv = 1.f;
        if (useMask) mv = (msk[(size_t)n * HW + y * W + xE] > 0) ? 1.f : 0.f;
#pragma unroll
        for (int m = 0; m < 4; ++m) {
            const int cb = co0 + waveco + m * 16 + lu * 4;
            const f32x4 bv = *reinterpret_cast<const f32x4*>(bias + cb);
            if (OUTMODE == 0) {
                float* o = (float*)outp + (size_t)n * coutTot * HW;
#pragma unroll
                for (int r = 0; r < 4; ++r)
                    o[(size_t)(cb + r) * HW + y * W + xE] = fmaxf(acc[m][nf][r] + bv[r], 0.f) * mv;
            } else {
                f16x4 h;
#pragma unroll
                for (int r = 0; r < 4; ++r)
                    h[r] = (_Float16)(fmaxf(acc[m][nf][r] + bv[r], 0.f) * mv);
                *reinterpret_cast<f16x4*>((_Float16*)outp + ((size_t)n * HW + y * W + xE) * Cout + cb) = h;
            }
        }
    }
}

// ---------------------------------------------------------------------------
// NHWC-fp16-input head conv (per image, H=W=128), fp16 MFMA, mask always.
// Block 128co x (16x16)px, 512 thr (8 waves, each 64co x 64px).
// Reg-prefetch pipeline: loads for cc+1 issued under the tap loop.
// OUTMODE 1: NHWC fp16 out; OUTMODE 0: fp32 NCHW out (for predictor).
// ---------------------------------------------------------------------------
template<int CCT, int OUTMODE>
__global__ __launch_bounds__(512, 2)
void conv_head_kernel(const _Float16* __restrict__ in, const _Float16* __restrict__ wp,
                      const float* __restrict__ bias, const int* __restrict__ msk,
                      void* __restrict__ outp)
{
    constexpr int Cin = CCT * 32;
    constexpr int OC = 512;
    __shared__ _Float16 Xs[1296 * 8];   // [item(18x18)][u(4)][8]
    const int tid = threadIdx.x;
    const int lane = tid & 63;
    const int wave = tid >> 6;
    const int lm = lane & 15;
    const int lu = lane >> 4;
    const int waveco = (wave & 1) * 64;
    const int wrow = (wave >> 1) * 4;          // 0,4,8,12
    const int co0 = blockIdx.y * 128;
    const int x0 = (blockIdx.x & 7) << 4;
    const int y0 = (blockIdx.x >> 3) << 4;

    int soff[3];
#pragma unroll
    for (int t = 0; t < 3; ++t) {
        int s = tid + t * 512;
        int item = s >> 2, u = s & 3;
        int row = item / 18;
        int col = item - row * 18;
        int y = y0 + row - 1, x = x0 + col - 1;
        soff[t] = (s < 1296 && y >= 0 && y < 128 && x >= 0 && x < 128)
                      ? ((y * 128 + x) * Cin + u * 8) : -1;
    }

    f32x4 acc[4][4];
#pragma unroll
    for (int m = 0; m < 4; ++m)
#pragma unroll
        for (int nf = 0; nf < 4; ++nf)
            acc[m][nf] = (f32x4){0.f, 0.f, 0.f, 0.f};

    f16x8 r0 = {}, r1 = {}, r2 = {};
    if (soff[0] >= 0) r0 = *reinterpret_cast<const f16x8*>(in + soff[0]);
    if (soff[1] >= 0) r1 = *reinterpret_cast<const f16x8*>(in + soff[1]);
    if (soff[2] >= 0) r2 = *reinterpret_cast<const f16x8*>(in + soff[2]);

    constexpr size_t tstride = (size_t)CCT * 4 * OC * 8;
    for (int cc = 0; cc < CCT; ++cc) {
        __syncthreads();
        *reinterpret_cast<f16x8*>(&Xs[tid * 8]) = r0;
        *reinterpret_cast<f16x8*>(&Xs[(tid + 512) * 8]) = r1;
        if (tid < 272) *reinterpret_cast<f16x8*>(&Xs[(tid + 1024) * 8]) = r2;
        __syncthreads();
        if (cc + 1 < CCT) {
            const int k = (cc + 1) * 32;
            r0 = (f16x8){}; r1 = (f16x8){}; r2 = (f16x8){};
            if (soff[0] >= 0) r0 = *reinterpret_cast<const f16x8*>(in + soff[0] + k);
            if (soff[1] >= 0) r1 = *reinterpret_cast<const f16x8*>(in + soff[1] + k);
            if (soff[2] >= 0) r2 = *reinterpret_cast<const f16x8*>(in + soff[2] + k);
        }
        const _Float16* wb = wp + (((size_t)cc * 4 + lu) * OC + co0 + waveco + lm) * 8;
#pragma unroll
        for (int tap = 0; tap < 9; ++tap) {
            const int dy = tap / 3, dx = tap % 3;
            const _Float16* wt = wb + (size_t)tap * tstride;
            f16x8 a[4], b[4];
#pragma unroll
            for (int m = 0; m < 4; ++m)
                a[m] = *reinterpret_cast<const f16x8*>(wt + m * 128);
#pragma unroll
            for (int nf = 0; nf < 4; ++nf)
                b[nf] = *reinterpret_cast<const f16x8*>(
                    &Xs[(((wrow + nf + dy) * 18 + lm + dx) * 4 + lu) * 8]);
#pragma unroll
            for (int m = 0; m < 4; ++m)
#pragma unroll
                for (int nf = 0; nf < 4; ++nf)
                    acc[m][nf] = __builtin_amdgcn_mfma_f32_16x16x32_f16(a[m], b[nf], acc[m][nf], 0, 0, 0);
        }
    }

    const int xE = x0 + lm;
#pragma unroll
    for (int nf = 0; nf < 4; ++nf) {
        const int y = y0 + wrow + nf;
        const float mv = (msk[y * 128 + xE] > 0) ? 1.f : 0.f;
#pragma unroll
        for (int m = 0; m < 4; ++m) {
            const int cb = co0 + waveco + m * 16 + lu * 4;
            const f32x4 bv = *reinterpret_cast<const f32x4*>(bias + cb);
            if (OUTMODE == 1) {
                f16x4 h;
#pragma unroll
                for (int r = 0; r < 4; ++r)
                    h[r] = (_Float16)(fmaxf(acc[m][nf][r] + bv[r], 0.f) * mv);
                *reinterpret_cast<f16x4*>((_Float16*)outp + (size_t)(y * 128 + xE) * OC + cb) = h;
            } else {
                float* o = (float*)outp;
#pragma unroll
                for (int r = 0; r < 4; ++r)
                    o[(size_t)(cb + r) * 16384 + y * 128 + xE] = fmaxf(acc[m][nf][r] + bv[r], 0.f) * mv;
            }
        }
    }
}

// Bilinear 2x upsample (align_corners=False => clamped 0.75/0.25 taps).
__global__ __launch_bounds__(256, 4)
void up2_kernel(const float* __restrict__ in, float* __restrict__ out,
                int Hin, int Win, int outChTot, int add)
{
    const int C = 256;
    const int Hout = Hin << 1, Wout = Win << 1;
    const int wsh = __ffs(Wout) - 1;
    const int hsh = __ffs(Hout) - 1;
    size_t total = (size_t)4 * C * Hout * Wout;
    for (size_t i = (size_t)blockIdx.x * THREADS + threadIdx.x; i < total;
         i += (size_t)gridDim.x * THREADS) {
        int x = (int)(i & (Wout - 1));
        size_t r = i >> wsh;
        int y = (int)(r & (Hout - 1));
        r >>= hsh;
        int c = (int)(r & (C - 1));
        int n = (int)(r >> 8);
        int iy = y >> 1, ix = x >> 1;
        int y2 = (y & 1) ? min(iy + 1, Hin - 1) : max(iy - 1, 0);
        int x2 = (x & 1) ? min(ix + 1, Win - 1) : max(ix - 1, 0);
        const float* p = in + (size_t)(n * C + c) * Hin * Win;
        float v00 = p[iy * Win + ix];
        float v01 = p[iy * Win + x2];
        float v10 = p[y2 * Win + ix];
        float v11 = p[y2 * Win + x2];
        float v = 0.5625f * v00 + 0.1875f * (v01 + v10) + 0.0625f * v11;
        size_t o = (((size_t)n * outChTot + c) * Hout + y) * Wout + x;
        if (add) out[o] += v;
        else out[o] = v;
    }
}

__global__ void coords_kernel(const float* __restrict__ rel, const float* __restrict__ abs_,
                              float* __restrict__ Xc)
{
    size_t i = (size_t)blockIdx.x * THREADS + threadIdx.x;
    const size_t total = 4ull * 4 * 128 * 128;
    if (i >= total) return;
    int x = (int)(i & 127);
    size_t r = i >> 7;
    int y = (int)(r & 127);
    r >>= 7;
    int c = (int)(r & 3);
    int n = (int)(r >> 2);
    const float* src = (c < 2) ? rel : abs_;
    int cc = c & 1;
    float v = src[(((size_t)n * 2 + cc) * 128 + y) * 128 + x];
    Xc[(((size_t)n * 260 + 256 + c) * 128 + y) * 128 + x] = v;
}

// 1x1 conv predictor, single image: [512][128][128] fp32 -> [75][128][128].
__global__ __launch_bounds__(256, 2)
void pred_kernel(const float* __restrict__ in, const float* __restrict__ w,
                 const float* __restrict__ bias, float* __restrict__ out)
{
    __shared__ float lw[25 * 512];
    const int co0 = blockIdx.y * 25;
    for (int idx = threadIdx.x; idx < 25 * 512; idx += THREADS)
        lw[idx] = w[(size_t)(co0 + idx / 512) * 512 + (idx & 511)];
    __syncthreads();
    int pix = blockIdx.x * THREADS + threadIdx.x;  // 0..16383
    int x = pix & 127;
    int y = pix >> 7;
    const float* ip = in + (size_t)y * 128 + x;
    float acc[25];
#pragma unroll
    for (int j = 0; j < 25; ++j) acc[j] = bias[co0 + j];
    for (int ci = 0; ci < 512; ci += 4) {
        float v0 = ip[(size_t)(ci + 0) * 16384];
        float v1 = ip[(size_t)(ci + 1) * 16384];
        float v2 = ip[(size_t)(ci + 2) * 16384];
        float v3 = ip[(size_t)(ci + 3) * 16384];
#pragma unroll
        for (int j = 0; j < 25; ++j) {
            float4 wv = *reinterpret_cast<const float4*>(&lw[j * 512 + ci]);
            acc[j] = fmaf(wv.x, v0, acc[j]);
            acc[j] = fmaf(wv.y, v1, acc[j]);
            acc[j] = fmaf(wv.z, v2, acc[j]);
            acc[j] = fmaf(wv.w, v3, acc[j]);
        }
    }
    float* op = out + (size_t)y * 128 + x;
#pragma unroll
    for (int j = 0; j < 25; ++j)
        op[(size_t)(co0 + j) * 16384] = acc[j];
}

extern "C" void kernel_launch(void* const* d_in, const int* in_sizes, int n_in,
                              void* d_out, int out_size, void* d_ws, size_t ws_size,
                              hipStream_t stream)
{
    const float* p2   = (const float*)d_in[0];
    const float* p3   = (const float*)d_in[1];
    const float* p4   = (const float*)d_in[2];
    const float* p5   = (const float*)d_in[3];
    const float* rel  = (const float*)d_in[4];
    const float* abs_ = (const float*)d_in[5];
    const int*   fg   = (const int*)d_in[6];
    const float* w_p2_0 = (const float*)d_in[7];
    const float* b_p2_0 = (const float*)d_in[8];
    const float* w_p3_0 = (const float*)d_in[9];
    const float* b_p3_0 = (const float*)d_in[10];
    const float* w_p4_0 = (const float*)d_in[11];
    const float* b_p4_0 = (const float*)d_in[12];
    const float* w_p4_1 = (const float*)d_in[13];
    const float* b_p4_1 = (const float*)d_in[14];
    const float* w_p5_0 = (const float*)d_in[15];
    const float* b_p5_0 = (const float*)d_in[16];
    const float* w_p5_1 = (const float*)d_in[17];
    const float* b_p5_1 = (const float*)d_in[18];
    const float* w_p5_2 = (const float*)d_in[19];
    const float* b_p5_2 = (const float*)d_in[20];
    const float* comb_w = (const float*)d_in[21];
    const float* comb_b = (const float*)d_in[22];
    const float* head_w0 = (const float*)d_in[23];
    const float* head_b0 = (const float*)d_in[24];
    const float* head_w  = (const float*)d_in[25];
    const float* head_b  = (const float*)d_in[26];
    const float* pred_w  = (const float*)d_in[27];
    const float* pred_b  = (const float*)d_in[28];

    // Workspace (float offsets; total 205.9 MB, < 245 MB known-good):
    //  Xc      [0, 17,039,360)          fp32 4x260ch@128^2
    //  combOut [17,039,360, 25,427,968) fp16 NHWC 4x[128^2][256]
    //  pingA   [25,427,968, 29,622,272) fp16 NHWC [128^2][512]
    //  pingB   [29,622,272, 33,816,576) fp16 NHWC [128^2][512]
    //  predIn  [33,816,576, 42,205,184) fp32 NCHW [512][128^2]
    //  wpScale [42,205,184, 42,605,184) packed fp16 scale/comb slot
    //  wpHead0 [42,605,184, 43,205,184) packed fp16 head0
    //  wpHead  [43,205,184, 51,462,720) packed fp16 head1..7
    //  temps: scale-phase only, overlap [17,039,360, 27,787,264) (dead pre-comb)
    float* ws = (float*)d_ws;
    float* Xc = ws;
    _Float16* combOut = (_Float16*)(ws + 17039360);
    _Float16* pingA   = (_Float16*)(ws + 25427968);
    _Float16* pingB   = (_Float16*)(ws + 29622272);
    float* predIn = ws + 33816576;
    _Float16* wpScale = (_Float16*)(ws + 42205184);
    _Float16* wpHead0 = (_Float16*)(ws + 42605184);
    _Float16* wpHead  = (_Float16*)(ws + 43205184);
    float* t64a = ws + 17039360;
    float* t64b = t64a + 4194304;
    float* t32a = t64b + 4194304;
    float* t32b = t32a + 1048576;
    float* t16  = t32b + 1048576;

    auto packw = [&](const float* w, _Float16* dst, int Cin, int Cout) {
        int CCl = (Cin + 31) / 32;
        int total = Cout * CCl * 4;
        pack_w16_kernel<<<dim3((total + THREADS - 1) / THREADS), dim3(THREADS), 0, stream>>>(
            w, dst, Cin, Cout, CCl);
    };
    auto convf = [&](const float* in, const _Float16* wpk, const float* bs, void* outp,
                     int Cin, int Cout, int H, int W, int coutTot, int useMask, int outmode) {
        int CCl = (Cin + 31) / 32;
        dim3 grid((W / 16) * (H / 8), Cout / 128, 4);
        if (outmode == 0)
            conv_f32_kernel<0><<<grid, dim3(256), 0, stream>>>(
                in, wpk, bs, fg, outp, Cin, CCl, Cout, H, W, coutTot, useMask);
        else
            conv_f32_kernel<1><<<grid, dim3(256), 0, stream>>>(
                in, wpk, bs, fg, outp, Cin, CCl, Cout, H, W, coutTot, useMask);
    };
    auto up2 = [&](const float* in, float* out, int Hin, int Win, int outChTot, int add) {
        size_t total = 4ull * 256 * 4 * Hin * Win;
        int blocks = (int)((total + THREADS - 1) / THREADS);
        if (blocks > 4096) blocks = 4096;
        up2_kernel<<<dim3(blocks), dim3(THREADS), 0, stream>>>(in, out, Hin, Win, outChTot, add);
    };

    // ---- pack head weights once (region disjoint from everything) ----
    packw(head_w0, wpHead0, 256, 512);
    for (int i = 0; i < 7; ++i)
        packw(head_w + (size_t)i * 512 * 512 * 9, wpHead + (size_t)i * 2359296, 512, 512);

    // ---- scale heads into Xc (260-channel concat buffer) ----
    packw(w_p2_0, wpScale, 256, 256);
    convf(p2, wpScale, b_p2_0, Xc, 256, 256, 128, 128, 260, 0, 0);
    coords_kernel<<<dim3(1024), dim3(THREADS), 0, stream>>>(rel, abs_, Xc);

    packw(w_p3_0, wpScale, 256, 256);
    convf(p3, wpScale, b_p3_0, t64a, 256, 256, 64, 64, 256, 0, 0);
    up2(t64a, Xc, 64, 64, 260, 1);

    packw(w_p4_0, wpScale, 256, 256);
    convf(p4, wpScale, b_p4_0, t32a, 256, 256, 32, 32, 256, 0, 0);
    up2(t32a, t64a, 32, 32, 256, 0);
    packw(w_p4_1, wpScale, 256, 256);
    convf(t64a, wpScale, b_p4_1, t64b, 256, 256, 64, 64, 256, 0, 0);
    up2(t64b, Xc, 64, 64, 260, 1);

    packw(w_p5_0, wpScale, 256, 256);
    convf(p5, wpScale, b_p5_0, t16, 256, 256, 16, 16, 256, 0, 0);
    up2(t16, t32a, 16, 16, 256, 0);
    packw(w_p5_1, wpScale, 256, 256);
    convf(t32a, wpScale, b_p5_1, t32b, 256, 256, 32, 32, 256, 0, 0);
    up2(t32b, t64a, 32, 32, 256, 0);
    packw(w_p5_2, wpScale, 256, 256);
    convf(t64a, wpScale, b_p5_2, t64b, 256, 256, 64, 64, 256, 0, 0);
    up2(t64b, Xc, 64, 64, 260, 1);

    // ---- comb conv (260 -> 256), relu + mask, NHWC fp16 out ----
    packw(comb_w, wpScale, 260, 256);
    convf(Xc, wpScale, comb_b, combOut, 260, 256, 128, 128, 256, 1, 1);

    // ---- per-image: 8 masked head convs (fp16 NHWC chain) + predictor ----
    for (int nn = 0; nn < 4; ++nn) {
        const _Float16* src0 = combOut + (size_t)nn * 16384 * 256;
        const int* mp = fg + (size_t)nn * 16384;
        dim3 hgrid(64, 4);
        conv_head_kernel<8, 1><<<hgrid, dim3(512), 0, stream>>>(
            src0, wpHead0, head_b0, mp, pingA);
        const _Float16* s = pingA;
        _Float16* d = pingB;
        for (int i = 0; i < 7; ++i) {
            const _Float16* wpl = wpHead + (size_t)i * 2359296;
            const float* bl = head_b + (size_t)i * 512;
            if (i == 6) {
                conv_head_kernel<16, 0><<<hgrid, dim3(512), 0, stream>>>(
                    s, wpl, bl, mp, predIn);
            } else {
                conv_head_kernel<16, 1><<<hgrid, dim3(512), 0, stream>>>(
                    s, wpl, bl, mp, d);
                _Float16* tmp = (_Float16*)s; s = d; d = tmp;
            }
        }
        pred_kernel<<<dim3(64, 3), dim3(THREADS), 0, stream>>>(
            predIn, pred_w, pred_b, (float*)d_out + (size_t)nn * 75 * 16384);
    }
}

// Round 4
// 4810.054 us; speedup vs baseline: 12.2069x; 1.0400x over previous
//
#include <hip/hip_runtime.h>
#include <cstdint>
#include <cstddef>

#define THREADS 256

typedef _Float16 f16x8 __attribute__((ext_vector_type(8)));
typedef _Float16 f16x4 __attribute__((ext_vector_type(4)));
typedef _Float16 f16x2 __attribute__((ext_vector_type(2)));
typedef float f32x4 __attribute__((ext_vector_type(4)));
typedef float f32x8 __attribute__((ext_vector_type(8)));

__device__ __forceinline__ void gll16(const void* g, void* l) {
    __builtin_amdgcn_global_load_lds(
        (const __attribute__((address_space(1))) unsigned int*)g,
        (__attribute__((address_space(3))) unsigned int*)l, 16, 0, 0);
}

// ---------------------------------------------------------------------------
// Weight pack: fp32 OIHW -> fp16 [tap][cc][u(4)][co][8]  (zero-fill ci>=Cin)
// ---------------------------------------------------------------------------
__global__ void pack_w16_kernel(const float* __restrict__ w, _Float16* __restrict__ wp,
                                int Cin, int Cout, int CC)
{
    int idx = blockIdx.x * THREADS + threadIdx.x;
    int total = Cout * CC * 4;
    if (idx >= total) return;
    int u = idx & 3;
    int cc = (idx >> 2) % CC;
    int co = (idx >> 2) / CC;
    int ci0 = cc * 32 + u * 8;
    for (int tap = 0; tap < 9; ++tap) {
        f16x8 v;
#pragma unroll
        for (int j = 0; j < 8; ++j) {
            int ci = ci0 + j;
            v[j] = (ci < Cin) ? (_Float16)w[((size_t)co * Cin + ci) * 9 + tap] : (_Float16)0.f;
        }
        *reinterpret_cast<f16x8*>(wp + ((((size_t)tap * CC + cc) * 4 + u) * Cout + co) * 8) = v;
    }
}

// ---------------------------------------------------------------------------
// NCHW fp32 -> NHWC fp16 transpose. Tile: 32 ci x 64 px. Grid (HW/64, C/32, N).
// ---------------------------------------------------------------------------
__global__ __launch_bounds__(256)
void t_kernel(const float* __restrict__ in, _Float16* __restrict__ out, int C, int HW)
{
    __shared__ _Float16 tile[64 * 32];
    const int n = blockIdx.z;
    const int c0 = blockIdx.y * 32;
    const int p0 = blockIdx.x * 64;
    const int tid = threadIdx.x;
    {
        int ci = tid >> 3;
        int j8 = (tid & 7) * 8;
        f32x8 v = *reinterpret_cast<const f32x8*>(in + ((size_t)n * C + c0 + ci) * HW + p0 + j8);
#pragma unroll
        for (int j = 0; j < 8; ++j)
            tile[(j8 + j) * 32 + ci] = (_Float16)v[j];
    }
    __syncthreads();
    {
        int px = tid >> 2;
        int u = tid & 3;
        f16x8 v = *reinterpret_cast<const f16x8*>(&tile[px * 32 + u * 8]);
        *reinterpret_cast<f16x8*>(out + ((size_t)n * HW + p0 + px) * C + c0 + u * 8) = v;
    }
}

// ---------------------------------------------------------------------------
// Unified implicit-GEMM 3x3 SAME conv, fp16 MFMA 16x16x32.
// Tile: 128 co x (16x16) px, 512 threads (8 waves: co-half x 4 row-bands).
// INF32=0: NHWC fp16 in, global_load_lds double-buffered (1 barrier/cc).
// INF32=1: NHWC fp32 in, reg-staged double-buffer (comb conv).
// OUTMODE 0: NHWC fp16 out, relu (+mask). 1: NHWC fp32 write, relu.
//         2: NHWC fp32 add, relu.
// ---------------------------------------------------------------------------
template<int INF32, int OUTMODE, int CC>
__global__ __launch_bounds__(512, 4)
void convu_kernel(const void* __restrict__ inv, const _Float16* __restrict__ wp,
                  const float* __restrict__ bias, const int* __restrict__ msk,
                  void* __restrict__ outp, int Cout, int H, int W,
                  int inCst, int outCst, int useMask)
{
    __shared__ _Float16 Xs[2 * 1344 * 8];

    const int tid = threadIdx.x;
    const int lane = tid & 63;
    const int wave = tid >> 6;
    const int lm = lane & 15;
    const int lu = lane >> 4;
    const int waveco = (wave & 1) * 64;
    const int wrow = (wave >> 1) * 4;
    const int n = blockIdx.z;
    const int co0 = blockIdx.y * 128;
    const int tpr = W >> 4;
    const int tx = blockIdx.x % tpr;
    const int ty = blockIdx.x / tpr;
    const int x0 = tx << 4;
    const int y0 = ty << 4;
    const int HW = H * W;

    int soff[3];
#pragma unroll
    for (int t = 0; t < 3; ++t) {
        int s = tid + t * 512;
        int item = s >> 2, u = s & 3;
        int row = item / 18, col = item - row * 18;
        int y = y0 + row - 1, x = x0 + col - 1;
        soff[t] = (s < 1296 && y >= 0 && y < H && x >= 0 && x < W)
                      ? ((n * HW + y * W + x) * inCst + u * 8) : -1;
    }

    f32x4 acc[4][4];
#pragma unroll
    for (int m = 0; m < 4; ++m)
#pragma unroll
        for (int nf = 0; nf < 4; ++nf)
            acc[m][nf] = (f32x4){0.f, 0.f, 0.f, 0.f};

    const size_t tstride = (size_t)CC * 4 * Cout * 8;
    f32x8 rr[3];

    if (INF32 == 0) {
        const _Float16* src = (const _Float16*)inv;
#pragma unroll
        for (int t = 0; t < 3; ++t) {   // pre-zero OOB slots in both buffers
            int s = tid + t * 512;
            if (s < 1296 && soff[t] < 0) {
                *reinterpret_cast<f16x8*>(&Xs[s * 8]) = (f16x8){};
                *reinterpret_cast<f16x8*>(&Xs[(1344 + s) * 8]) = (f16x8){};
            }
        }
#pragma unroll
        for (int t = 0; t < 3; ++t) {   // prologue stage cc=0 -> buf0
            int s = tid + t * 512;
            if (s < 1296 && soff[t] >= 0)
                gll16(src + soff[t], &Xs[(t * 512 + (tid & ~63)) * 8]);
        }
    } else {
        const float* srcf = (const float*)inv;
#pragma unroll
        for (int t = 0; t < 3; ++t) {
            int s = tid + t * 512;
            rr[t] = (f32x8){};
            if (s < 1296 && soff[t] >= 0)
                rr[t] = *reinterpret_cast<const f32x8*>(srcf + soff[t]);
        }
#pragma unroll
        for (int t = 0; t < 3; ++t) {
            int s = tid + t * 512;
            if (s < 1296) {
                f16x8 h;
#pragma unroll
                for (int j = 0; j < 8; ++j) h[j] = (_Float16)rr[t][j];
                *reinterpret_cast<f16x8*>(&Xs[s * 8]) = h;
            }
        }
    }
    __syncthreads();

    int bsel = 0;
    for (int cc = 0; cc < CC; ++cc) {
        // ---- issue prefetch for cc+1 into buf^1 ----
        if (cc + 1 < CC) {
            if (INF32 == 0) {
                const _Float16* src = (const _Float16*)inv;
#pragma unroll
                for (int t = 0; t < 3; ++t) {
                    int s = tid + t * 512;
                    if (s < 1296 && soff[t] >= 0)
                        gll16(src + soff[t] + (cc + 1) * 32,
                              &Xs[((bsel ^ 1) * 1344 + t * 512 + (tid & ~63)) * 8]);
                }
            } else {
                const float* srcf = (const float*)inv;
#pragma unroll
                for (int t = 0; t < 3; ++t) {
                    int s = tid + t * 512;
                    rr[t] = (f32x8){};
                    if (s < 1296 && soff[t] >= 0)
                        rr[t] = *reinterpret_cast<const f32x8*>(srcf + soff[t] + (cc + 1) * 32);
                }
            }
        }
        // ---- compute on buf bsel ----
        {
            const int xbase = bsel * 1344;
            const _Float16* wb = wp + (((size_t)cc * 4 + lu) * Cout + co0 + waveco + lm) * 8;
#pragma unroll
            for (int tap = 0; tap < 9; ++tap) {
                const int dy = tap / 3, dx = tap % 3;
                const _Float16* wt = wb + (size_t)tap * tstride;
                f16x8 a[4], b[4];
#pragma unroll
                for (int m = 0; m < 4; ++m)
                    a[m] = *reinterpret_cast<const f16x8*>(wt + m * 128);
#pragma unroll
                for (int nf = 0; nf < 4; ++nf) {
                    int slot = ((wrow + nf + dy) * 18 + lm + dx) * 4 + lu;
                    b[nf] = *reinterpret_cast<const f16x8*>(&Xs[(xbase + slot) * 8]);
                }
#pragma unroll
                for (int m = 0; m < 4; ++m)
#pragma unroll
                    for (int nf = 0; nf < 4; ++nf)
                        acc[m][nf] = __builtin_amdgcn_mfma_f32_16x16x32_f16(a[m], b[nf], acc[m][nf], 0, 0, 0);
            }
        }
        // ---- reg-path: write prefetched cc+1 into buf^1 ----
        if (INF32 == 1 && cc + 1 < CC) {
#pragma unroll
            for (int t = 0; t < 3; ++t) {
                int s = tid + t * 512;
                if (s < 1296) {
                    f16x8 h;
#pragma unroll
                    for (int j = 0; j < 8; ++j) h[j] = (_Float16)rr[t][j];
                    *reinterpret_cast<f16x8*>(&Xs[((bsel ^ 1) * 1344 + s) * 8]) = h;
                }
            }
        }
        __syncthreads();
        bsel ^= 1;
    }

    // ---- epilogue ----
    const int xE = x0 + lm;
    const size_t nHW = (size_t)n * HW;
#pragma unroll
    for (int nf = 0; nf < 4; ++nf) {
        const int y = y0 + wrow + nf;
        float mv = 1.f;
        if (useMask) mv = (msk[nHW + y * W + xE] > 0) ? 1.f : 0.f;
        const size_t pixo = (nHW + (size_t)y * W + xE) * outCst;
#pragma unroll
        for (int m = 0; m < 4; ++m) {
            const int cb = co0 + waveco + m * 16 + lu * 4;
            const f32x4 bv = *reinterpret_cast<const f32x4*>(bias + cb);
            if (OUTMODE == 0) {
                f16x4 h;
#pragma unroll
                for (int r = 0; r < 4; ++r)
                    h[r] = (_Float16)(fmaxf(acc[m][nf][r] + bv[r], 0.f) * mv);
                *reinterpret_cast<f16x4*>((_Float16*)outp + pixo + cb) = h;
            } else if (OUTMODE == 1) {
                f32x4 v;
#pragma unroll
                for (int r = 0; r < 4; ++r)
                    v[r] = fmaxf(acc[m][nf][r] + bv[r], 0.f);
                *reinterpret_cast<f32x4*>((float*)outp + pixo + cb) = v;
            } else {
                f32x4 old = *reinterpret_cast<const f32x4*>((float*)outp + pixo + cb);
#pragma unroll
                for (int r = 0; r < 4; ++r)
                    old[r] += fmaxf(acc[m][nf][r] + bv[r], 0.f);
                *reinterpret_cast<f32x4*>((float*)outp + pixo + cb) = old;
            }
        }
    }
}

// ---------------------------------------------------------------------------
// fp16 NHWC 2x bilinear upsample (align_corners=False -> clamped 0.75/0.25).
// ---------------------------------------------------------------------------
__global__ void up2h_kernel(const _Float16* __restrict__ in, _Float16* __restrict__ out,
                            int Hin, int Win)
{
    const int Wout = Win << 1, Hout = Hin << 1;
    const int lw = __ffs(Wout) - 1, lh = __ffs(Hout) - 1;
    int i = blockIdx.x * THREADS + threadIdx.x;
    if (i >= 4 * Hout * Wout * 32) return;
    int u = i & 31;
    int p = i >> 5;
    int x = p & (Wout - 1);
    int y = (p >> lw) & (Hout - 1);
    int n = p >> (lw + lh);
    int iy = y >> 1, ix = x >> 1;
    int y2 = (y & 1) ? min(iy + 1, Hin - 1) : max(iy - 1, 0);
    int x2 = (x & 1) ? min(ix + 1, Win - 1) : max(ix - 1, 0);
    const _Float16* base = in + ((size_t)n * Hin * Win) * 256 + u * 8;
    f16x8 v00 = *reinterpret_cast<const f16x8*>(base + (iy * Win + ix) * 256);
    f16x8 v01 = *reinterpret_cast<const f16x8*>(base + (iy * Win + x2) * 256);
    f16x8 v10 = *reinterpret_cast<const f16x8*>(base + (y2 * Win + ix) * 256);
    f16x8 v11 = *reinterpret_cast<const f16x8*>(base + (y2 * Win + x2) * 256);
    f16x8 o;
#pragma unroll
    for (int j = 0; j < 8; ++j) {
        float v = 0.5625f * (float)v00[j] + 0.1875f * ((float)v01[j] + (float)v10[j])
                + 0.0625f * (float)v11[j];
        o[j] = (_Float16)v;
    }
    *reinterpret_cast<f16x8*>(out + (((size_t)n * Hout * Wout) + y * Wout + x) * 256 + u * 8) = o;
}

// fp32 NHWC 64^2 -> 128^2 upsample-ADD into Xc (stride 288, channels 0..255).
__global__ void up2add_kernel(const float* __restrict__ in, float* __restrict__ Xc)
{
    int i = blockIdx.x * THREADS + threadIdx.x;
    if (i >= 4 * 16384 * 32) return;
    int u = i & 31;
    int p = i >> 5;
    int x = p & 127;
    int y = (p >> 7) & 127;
    int n = p >> 14;
    int iy = y >> 1, ix = x >> 1;
    int y2 = (y & 1) ? min(iy + 1, 63) : max(iy - 1, 0);
    int x2 = (x & 1) ? min(ix + 1, 63) : max(ix - 1, 0);
    const float* base = in + ((size_t)n * 4096) * 256 + u * 8;
    f32x8 v00 = *reinterpret_cast<const f32x8*>(base + (iy * 64 + ix) * 256);
    f32x8 v01 = *reinterpret_cast<const f32x8*>(base + (iy * 64 + x2) * 256);
    f32x8 v10 = *reinterpret_cast<const f32x8*>(base + (y2 * 64 + ix) * 256);
    f32x8 v11 = *reinterpret_cast<const f32x8*>(base + (y2 * 64 + x2) * 256);
    float* dst = Xc + ((size_t)n * 16384 + y * 128 + x) * 288 + u * 8;
    f32x8 d = *reinterpret_cast<const f32x8*>(dst);
#pragma unroll
    for (int j = 0; j < 8; ++j)
        d[j] += 0.5625f * v00[j] + 0.1875f * (v01[j] + v10[j]) + 0.0625f * v11[j];
    *reinterpret_cast<f32x8*>(dst) = d;
}

// Coords into Xc channels 256..259; zero channels 260..287.
__global__ void coords2_kernel(const float* __restrict__ rel, const float* __restrict__ abs_,
                               float* __restrict__ Xc)
{
    int i = blockIdx.x * THREADS + threadIdx.x;
    if (i >= 4 * 16384) return;
    int px = i & 16383;
    int n = i >> 14;
    float* dst = Xc + ((size_t)n * 16384 + px) * 288 + 256;
    dst[0] = rel[((size_t)n * 2 + 0) * 16384 + px];
    dst[1] = rel[((size_t)n * 2 + 1) * 16384 + px];
    dst[2] = abs_[((size_t)n * 2 + 0) * 16384 + px];
    dst[3] = abs_[((size_t)n * 2 + 1) * 16384 + px];
#pragma unroll
    for (int c = 4; c < 32; ++c) dst[c] = 0.f;
}

// 1x1 predictor: NHWC fp16 [n][16384][512] -> NCHW fp32 [n][75][16384].
__global__ __launch_bounds__(256)
void predh_kernel(const _Float16* __restrict__ in, const float* __restrict__ w,
                  const float* __restrict__ bias, float* __restrict__ out)
{
    __shared__ _Float16 lw[25 * 512];
    const int co0 = blockIdx.y * 25;
    const int n = blockIdx.z;
    for (int idx = threadIdx.x; idx < 25 * 512; idx += 256)
        lw[idx] = (_Float16)w[(size_t)(co0 + idx / 512) * 512 + (idx & 511)];
    __syncthreads();
    int px = blockIdx.x * 256 + threadIdx.x;
    const _Float16* ip = in + ((size_t)n * 16384 + px) * 512;
    float acc[25];
#pragma unroll
    for (int j = 0; j < 25; ++j) acc[j] = bias[co0 + j];
    for (int g = 0; g < 64; ++g) {
        union { f16x8 v; f16x2 p[4]; } xv;
        xv.v = *reinterpret_cast<const f16x8*>(ip + g * 8);
#pragma unroll
        for (int j = 0; j < 25; ++j) {
            union { f16x8 v; f16x2 p[4]; } wv;
            wv.v = *reinterpret_cast<const f16x8*>(&lw[j * 512 + g * 8]);
#if __has_builtin(__builtin_amdgcn_fdot2)
#pragma unroll
            for (int k = 0; k < 4; ++k)
                acc[j] = __builtin_amdgcn_fdot2(xv.p[k], wv.p[k], acc[j], false);
#else
#pragma unroll
            for (int k = 0; k < 8; ++k)
                acc[j] = fmaf((float)xv.v[k], (float)wv.v[k], acc[j]);
#endif
        }
    }
    float* op = out + ((size_t)n * 75) * 16384 + px;
#pragma unroll
    for (int j = 0; j < 25; ++j)
        op[(size_t)(co0 + j) * 16384] = acc[j];
}

extern "C" void kernel_launch(void* const* d_in, const int* in_sizes, int n_in,
                              void* d_out, int out_size, void* d_ws, size_t ws_size,
                              hipStream_t stream)
{
    const float* p2   = (const float*)d_in[0];
    const float* p3   = (const float*)d_in[1];
    const float* p4   = (const float*)d_in[2];
    const float* p5   = (const float*)d_in[3];
    const float* rel  = (const float*)d_in[4];
    const float* abs_ = (const float*)d_in[5];
    const int*   fg   = (const int*)d_in[6];
    const float* w_p2_0 = (const float*)d_in[7];
    const float* b_p2_0 = (const float*)d_in[8];
    const float* w_p3_0 = (const float*)d_in[9];
    const float* b_p3_0 = (const float*)d_in[10];
    const float* w_p4_0 = (const float*)d_in[11];
    const float* b_p4_0 = (const float*)d_in[12];
    const float* w_p4_1 = (const float*)d_in[13];
    const float* b_p4_1 = (const float*)d_in[14];
    const float* w_p5_0 = (const float*)d_in[15];
    const float* b_p5_0 = (const float*)d_in[16];
    const float* w_p5_1 = (const float*)d_in[17];
    const float* b_p5_1 = (const float*)d_in[18];
    const float* w_p5_2 = (const float*)d_in[19];
    const float* b_p5_2 = (const float*)d_in[20];
    const float* comb_w = (const float*)d_in[21];
    const float* comb_b = (const float*)d_in[22];
    const float* head_w0 = (const float*)d_in[23];
    const float* head_b0 = (const float*)d_in[24];
    const float* head_w  = (const float*)d_in[25];
    const float* head_b  = (const float*)d_in[26];
    const float* pred_w  = (const float*)d_in[27];
    const float* pred_b  = (const float*)d_in[28];

    // Workspace layout (float offsets). Total 57,081,856 floats = 228.3 MB.
    //  A: Xc (NHWC-288 fp32) -> later pingA (fp16 4x[16384][512])
    //  B: pingB
    //  D: p2h -> scale temps -> combOut (all phases disjoint in time)
    //  E/F/G: p3h/p4h/p5h    H: wpScale slot    I: wpHead0    J: wpHead x7
    float* ws = (float*)d_ws;
    float*    Xc      = ws;                                  // 18,874,368
    _Float16* pingA   = (_Float16*)ws;
    _Float16* pingB   = (_Float16*)(ws + 18874368);          // 16,777,216
    float*    regD    = ws + 35651584;                       //  8,388,608
    _Float16* p2h     = (_Float16*)regD;
    _Float16* combOut = (_Float16*)regD;
    float*    t64sum  = regD;
    _Float16* t64b    = (_Float16*)(regD + 4194304);
    _Float16* t64c    = (_Float16*)(regD + 5242880);
    _Float16* t32a    = (_Float16*)(regD + 6291456);
    _Float16* t32b    = (_Float16*)(regD + 6553600);
    _Float16* t32c    = (_Float16*)(regD + 6815744);
    _Float16* t16a    = (_Float16*)(regD + 7077888);
    _Float16* p3h     = (_Float16*)(ws + 44040192);          //  2,097,152
    _Float16* p4h     = (_Float16*)(ws + 46137344);          //    524,288
    _Float16* p5h     = (_Float16*)(ws + 46661632);          //    131,072
    _Float16* wpScale = (_Float16*)(ws + 46792704);          //  1,441,792
    _Float16* wpHead0 = (_Float16*)(ws + 48234496);          //    589,824
    _Float16* wpHead  = (_Float16*)(ws + 48824320);          //  8,257,536

    auto packw = [&](const float* w, _Float16* dst, int Cin, int Cout) {
        int CCl = (Cin + 31) / 32;
        int total = Cout * CCl * 4;
        pack_w16_kernel<<<dim3((total + THREADS - 1) / THREADS), dim3(THREADS), 0, stream>>>(
            w, dst, Cin, Cout, CCl);
    };
    auto transp = [&](const float* in, _Float16* out, int C, int HW) {
        t_kernel<<<dim3(HW / 64, C / 32, 4), dim3(256), 0, stream>>>(in, out, C, HW);
    };
    auto convu = [&](const void* in, const _Float16* wpk, const float* bs, void* outp,
                     int inf32, int outmode, int CCv, int Cout, int H, int W,
                     int inCst, int outCst, int useMask) {
        dim3 grid((W / 16) * (H / 16), Cout / 128, 4);
        dim3 blk(512);
        if (inf32 == 0 && outmode == 0 && CCv == 8)
            convu_kernel<0, 0, 8><<<grid, blk, 0, stream>>>(in, wpk, bs, fg, outp, Cout, H, W, inCst, outCst, useMask);
        else if (inf32 == 0 && outmode == 0 && CCv == 16)
            convu_kernel<0, 0, 16><<<grid, blk, 0, stream>>>(in, wpk, bs, fg, outp, Cout, H, W, inCst, outCst, useMask);
        else if (inf32 == 0 && outmode == 1 && CCv == 8)
            convu_kernel<0, 1, 8><<<grid, blk, 0, stream>>>(in, wpk, bs, fg, outp, Cout, H, W, inCst, outCst, useMask);
        else if (inf32 == 0 && outmode == 2 && CCv == 8)
            convu_kernel<0, 2, 8><<<grid, blk, 0, stream>>>(in, wpk, bs, fg, outp, Cout, H, W, inCst, outCst, useMask);
        else
            convu_kernel<1, 0, 9><<<grid, blk, 0, stream>>>(in, wpk, bs, fg, outp, Cout, H, W, inCst, outCst, useMask);
    };
    auto up2h = [&](const _Float16* in, _Float16* out, int Hin, int Win) {
        int total = 4 * (Hin * 2) * (Win * 2) * 32;
        up2h_kernel<<<dim3((total + THREADS - 1) / THREADS), dim3(THREADS), 0, stream>>>(
            in, out, Hin, Win);
    };

    // ---- pack head weights (persistent) ----
    packw(head_w0, wpHead0, 256, 512);
    for (int i = 0; i < 7; ++i)
        packw(head_w + (size_t)i * 512 * 512 * 9, wpHead + (size_t)i * 2359296, 512, 512);

    // ---- transpose FPN inputs to NHWC fp16 ----
    transp(p2, p2h, 256, 16384);
    transp(p3, p3h, 256, 4096);
    transp(p4, p4h, 256, 1024);
    transp(p5, p5h, 256, 256);

    // ---- p2 scale head -> Xc (fp32 NHWC-288), coords+zeropad ----
    packw(w_p2_0, wpScale, 256, 256);
    convu(p2h, wpScale, b_p2_0, Xc, 0, 1, 8, 256, 128, 128, 256, 288, 0);
    coords2_kernel<<<dim3(256), dim3(THREADS), 0, stream>>>(rel, abs_, Xc);

    // ---- p3 -> t64sum (write) ----
    packw(w_p3_0, wpScale, 256, 256);
    convu(p3h, wpScale, b_p3_0, t64sum, 0, 1, 8, 256, 64, 64, 256, 256, 0);

    // ---- p4 chain: conv32 -> up -> conv64 (add into t64sum) ----
    packw(w_p4_0, wpScale, 256, 256);
    convu(p4h, wpScale, b_p4_0, t32a, 0, 0, 8, 256, 32, 32, 256, 256, 0);
    up2h(t32a, t64b, 32, 32);
    packw(w_p4_1, wpScale, 256, 256);
    convu(t64b, wpScale, b_p4_1, t64sum, 0, 2, 8, 256, 64, 64, 256, 256, 0);

    // ---- p5 chain: conv16 -> up -> conv32 -> up -> conv64 (add) ----
    packw(w_p5_0, wpScale, 256, 256);
    convu(p5h, wpScale, b_p5_0, t16a, 0, 0, 8, 256, 16, 16, 256, 256, 0);
    up2h(t16a, t32b, 16, 16);
    packw(w_p5_1, wpScale, 256, 256);
    convu(t32b, wpScale, b_p5_1, t32c, 0, 0, 8, 256, 32, 32, 256, 256, 0);
    up2h(t32c, t64c, 32, 32);
    packw(w_p5_2, wpScale, 256, 256);
    convu(t64c, wpScale, b_p5_2, t64sum, 0, 2, 8, 256, 64, 64, 256, 256, 0);

    // ---- single upsample-add of merged 64^2 sum into Xc ----
    up2add_kernel<<<dim3(8192), dim3(THREADS), 0, stream>>>(t64sum, Xc);

    // ---- comb conv (Xc fp32 NHWC-288 -> combOut fp16 NHWC-256), relu+mask ----
    packw(comb_w, wpScale, 260, 256);
    convu(Xc, wpScale, comb_b, combOut, 1, 0, 9, 256, 128, 128, 288, 256, 1);

    // ---- head chain, batched over 4 images ----
    convu(combOut, wpHead0, head_b0, pingA, 0, 0, 8, 512, 128, 128, 256, 512, 1);
    {
        _Float16* s = pingA;
        _Float16* d = pingB;
        for (int i = 0; i < 7; ++i) {
            convu(s, wpHead + (size_t)i * 2359296, head_b + (size_t)i * 512,
                  d, 0, 0, 16, 512, 128, 128, 512, 512, 1);
            _Float16* tmp = s; s = d; d = tmp;
        }
    }

    // ---- predictor (reads pingB), batched ----
    predh_kernel<<<dim3(64, 3, 4), dim3(256), 0, stream>>>(pingB, pred_w, pred_b, (float*)d_out);
}

// Round 5
// 3175.574 us; speedup vs baseline: 18.4898x; 1.5147x over previous
//
#include <hip/hip_runtime.h>
#include <cstdint>
#include <cstddef>

#define THREADS 256

typedef _Float16 f16x8 __attribute__((ext_vector_type(8)));
typedef _Float16 f16x4 __attribute__((ext_vector_type(4)));
typedef _Float16 f16x2 __attribute__((ext_vector_type(2)));
typedef float f32x4 __attribute__((ext_vector_type(4)));
typedef float f32x8 __attribute__((ext_vector_type(8)));

__device__ __forceinline__ void gll16(const void* g, void* l) {
    __builtin_amdgcn_global_load_lds(
        (const __attribute__((address_space(1))) unsigned int*)g,
        (__attribute__((address_space(3))) unsigned int*)l, 16, 0, 0);
}

// ---------------------------------------------------------------------------
// Weight pack (old format, for scale/comb convs):
// fp32 OIHW -> fp16 [tap][cc][u(4)][co][8]  (zero-fill ci>=Cin)
// ---------------------------------------------------------------------------
__global__ void pack_w16_kernel(const float* __restrict__ w, _Float16* __restrict__ wp,
                                int Cin, int Cout, int CC)
{
    int idx = blockIdx.x * THREADS + threadIdx.x;
    int total = Cout * CC * 4;
    if (idx >= total) return;
    int u = idx & 3;
    int cc = (idx >> 2) % CC;
    int co = (idx >> 2) / CC;
    int ci0 = cc * 32 + u * 8;
    for (int tap = 0; tap < 9; ++tap) {
        f16x8 v;
#pragma unroll
        for (int j = 0; j < 8; ++j) {
            int ci = ci0 + j;
            v[j] = (ci < Cin) ? (_Float16)w[((size_t)co * Cin + ci) * 9 + tap] : (_Float16)0.f;
        }
        *reinterpret_cast<f16x8*>(wp + ((((size_t)tap * CC + cc) * 4 + u) * Cout + co) * 8) = v;
    }
}

// ---------------------------------------------------------------------------
// Head-GEMM weight pack: fp32 OIHW -> fp16 [kstep][gy(2)][chunk 2048][8]
// K linearized tap-major (k = tap*Cin + ci), 64-wide K-steps.
// Bank-swizzle baked in: chunk (r*8+kc) holds k-slice (kc ^ (r&7)).
// ---------------------------------------------------------------------------
__global__ void pack_whead_kernel(const float* __restrict__ w, _Float16* __restrict__ wp,
                                  int Cin)
{
    const int NSTEP = 9 * (Cin / 64);
    int idx = blockIdx.x * THREADS + threadIdx.x;
    int total = 512 * NSTEP * 8;
    if (idx >= total) return;
    int kc = idx & 7;
    int t = (idx >> 3) % NSTEP;
    int co = (idx >> 3) / NSTEP;
    int gy = co >> 8;
    int r = co & 255;
    int kcs = kc ^ (r & 7);
    int k = t * 64 + kcs * 8;
    int tap = k / Cin;
    int cib = k - tap * Cin;
    f16x8 v;
#pragma unroll
    for (int j = 0; j < 8; ++j)
        v[j] = (_Float16)w[((size_t)co * Cin + cib + j) * 9 + tap];
    *reinterpret_cast<f16x8*>(wp + ((size_t)(t * 2 + gy) * 2048 + r * 8 + kc) * 8) = v;
}

__global__ void zerows_kernel(float* __restrict__ p)
{
    p[blockIdx.x * THREADS + threadIdx.x] = 0.f;
}

// ---------------------------------------------------------------------------
// NCHW fp32 -> NHWC fp16 transpose. Tile: 32 ci x 64 px. Grid (HW/64, C/32, N).
// ---------------------------------------------------------------------------
__global__ __launch_bounds__(256)
void t_kernel(const float* __restrict__ in, _Float16* __restrict__ out, int C, int HW)
{
    __shared__ _Float16 tile[64 * 32];
    const int n = blockIdx.z;
    const int c0 = blockIdx.y * 32;
    const int p0 = blockIdx.x * 64;
    const int tid = threadIdx.x;
    {
        int ci = tid >> 3;
        int j8 = (tid & 7) * 8;
        f32x8 v = *reinterpret_cast<const f32x8*>(in + ((size_t)n * C + c0 + ci) * HW + p0 + j8);
#pragma unroll
        for (int j = 0; j < 8; ++j)
            tile[(j8 + j) * 32 + ci] = (_Float16)v[j];
    }
    __syncthreads();
    {
        int px = tid >> 2;
        int u = tid & 3;
        f16x8 v = *reinterpret_cast<const f16x8*>(&tile[px * 32 + u * 8]);
        *reinterpret_cast<f16x8*>(out + ((size_t)n * HW + p0 + px) * C + c0 + u * 8) = v;
    }
}

// ---------------------------------------------------------------------------
// Old unified conv (kept for scale heads + comb conv). See round-4 comments.
// ---------------------------------------------------------------------------
template<int INF32, int OUTMODE, int CC>
__global__ __launch_bounds__(512, 4)
void convu_kernel(const void* __restrict__ inv, const _Float16* __restrict__ wp,
                  const float* __restrict__ bias, const int* __restrict__ msk,
                  void* __restrict__ outp, int Cout, int H, int W,
                  int inCst, int outCst, int useMask)
{
    __shared__ _Float16 Xs[2 * 1344 * 8];

    const int tid = threadIdx.x;
    const int lane = tid & 63;
    const int wave = tid >> 6;
    const int lm = lane & 15;
    const int lu = lane >> 4;
    const int waveco = (wave & 1) * 64;
    const int wrow = (wave >> 1) * 4;
    const int n = blockIdx.z;
    const int co0 = blockIdx.y * 128;
    const int tpr = W >> 4;
    const int tx = blockIdx.x % tpr;
    const int ty = blockIdx.x / tpr;
    const int x0 = tx << 4;
    const int y0 = ty << 4;
    const int HW = H * W;

    int soff[3];
#pragma unroll
    for (int t = 0; t < 3; ++t) {
        int s = tid + t * 512;
        int item = s >> 2, u = s & 3;
        int row = item / 18, col = item - row * 18;
        int y = y0 + row - 1, x = x0 + col - 1;
        soff[t] = (s < 1296 && y >= 0 && y < H && x >= 0 && x < W)
                      ? ((n * HW + y * W + x) * inCst + u * 8) : -1;
    }

    f32x4 acc[4][4];
#pragma unroll
    for (int m = 0; m < 4; ++m)
#pragma unroll
        for (int nf = 0; nf < 4; ++nf)
            acc[m][nf] = (f32x4){0.f, 0.f, 0.f, 0.f};

    const size_t tstride = (size_t)CC * 4 * Cout * 8;
    f32x8 rr[3];

    if (INF32 == 0) {
        const _Float16* src = (const _Float16*)inv;
#pragma unroll
        for (int t = 0; t < 3; ++t) {
            int s = tid + t * 512;
            if (s < 1296 && soff[t] < 0) {
                *reinterpret_cast<f16x8*>(&Xs[s * 8]) = (f16x8){};
                *reinterpret_cast<f16x8*>(&Xs[(1344 + s) * 8]) = (f16x8){};
            }
        }
#pragma unroll
        for (int t = 0; t < 3; ++t) {
            int s = tid + t * 512;
            if (s < 1296 && soff[t] >= 0)
                gll16(src + soff[t], &Xs[(t * 512 + (tid & ~63)) * 8]);
        }
    } else {
        const float* srcf = (const float*)inv;
#pragma unroll
        for (int t = 0; t < 3; ++t) {
            int s = tid + t * 512;
            rr[t] = (f32x8){};
            if (s < 1296 && soff[t] >= 0)
                rr[t] = *reinterpret_cast<const f32x8*>(srcf + soff[t]);
        }
#pragma unroll
        for (int t = 0; t < 3; ++t) {
            int s = tid + t * 512;
            if (s < 1296) {
                f16x8 h;
#pragma unroll
                for (int j = 0; j < 8; ++j) h[j] = (_Float16)rr[t][j];
                *reinterpret_cast<f16x8*>(&Xs[s * 8]) = h;
            }
        }
    }
    __syncthreads();

    int bsel = 0;
    for (int cc = 0; cc < CC; ++cc) {
        if (cc + 1 < CC) {
            if (INF32 == 0) {
                const _Float16* src = (const _Float16*)inv;
#pragma unroll
                for (int t = 0; t < 3; ++t) {
                    int s = tid + t * 512;
                    if (s < 1296 && soff[t] >= 0)
                        gll16(src + soff[t] + (cc + 1) * 32,
                              &Xs[((bsel ^ 1) * 1344 + t * 512 + (tid & ~63)) * 8]);
                }
            } else {
                const float* srcf = (const float*)inv;
#pragma unroll
                for (int t = 0; t < 3; ++t) {
                    int s = tid + t * 512;
                    rr[t] = (f32x8){};
                    if (s < 1296 && soff[t] >= 0)
                        rr[t] = *reinterpret_cast<const f32x8*>(srcf + soff[t] + (cc + 1) * 32);
                }
            }
        }
        {
            const int xbase = bsel * 1344;
            const _Float16* wb = wp + (((size_t)cc * 4 + lu) * Cout + co0 + waveco + lm) * 8;
#pragma unroll
            for (int tap = 0; tap < 9; ++tap) {
                const int dy = tap / 3, dx = tap % 3;
                const _Float16* wt = wb + (size_t)tap * tstride;
                f16x8 a[4], b[4];
#pragma unroll
                for (int m = 0; m < 4; ++m)
                    a[m] = *reinterpret_cast<const f16x8*>(wt + m * 128);
#pragma unroll
                for (int nf = 0; nf < 4; ++nf) {
                    int slot = ((wrow + nf + dy) * 18 + lm + dx) * 4 + lu;
                    b[nf] = *reinterpret_cast<const f16x8*>(&Xs[(xbase + slot) * 8]);
                }
#pragma unroll
                for (int m = 0; m < 4; ++m)
#pragma unroll
                    for (int nf = 0; nf < 4; ++nf)
                        acc[m][nf] = __builtin_amdgcn_mfma_f32_16x16x32_f16(a[m], b[nf], acc[m][nf], 0, 0, 0);
            }
        }
        if (INF32 == 1 && cc + 1 < CC) {
#pragma unroll
            for (int t = 0; t < 3; ++t) {
                int s = tid + t * 512;
                if (s < 1296) {
                    f16x8 h;
#pragma unroll
                    for (int j = 0; j < 8; ++j) h[j] = (_Float16)rr[t][j];
                    *reinterpret_cast<f16x8*>(&Xs[((bsel ^ 1) * 1344 + s) * 8]) = h;
                }
            }
        }
        __syncthreads();
        bsel ^= 1;
    }

    const int xE = x0 + lm;
    const size_t nHW = (size_t)n * HW;
#pragma unroll
    for (int nf = 0; nf < 4; ++nf) {
        const int y = y0 + wrow + nf;
        float mv = 1.f;
        if (useMask) mv = (msk[nHW + y * W + xE] > 0) ? 1.f : 0.f;
        const size_t pixo = (nHW + (size_t)y * W + xE) * outCst;
#pragma unroll
        for (int m = 0; m < 4; ++m) {
            const int cb = co0 + waveco + m * 16 + lu * 4;
            const f32x4 bv = *reinterpret_cast<const f32x4*>(bias + cb);
            if (OUTMODE == 0) {
                f16x4 h;
#pragma unroll
                for (int r = 0; r < 4; ++r)
                    h[r] = (_Float16)(fmaxf(acc[m][nf][r] + bv[r], 0.f) * mv);
                *reinterpret_cast<f16x4*>((_Float16*)outp + pixo + cb) = h;
            } else if (OUTMODE == 1) {
                f32x4 v;
#pragma unroll
                for (int r = 0; r < 4; ++r)
                    v[r] = fmaxf(acc[m][nf][r] + bv[r], 0.f);
                *reinterpret_cast<f32x4*>((float*)outp + pixo + cb) = v;
            } else {
                f32x4 old = *reinterpret_cast<const f32x4*>((float*)outp + pixo + cb);
#pragma unroll
                for (int r = 0; r < 4; ++r)
                    old[r] += fmaxf(acc[m][nf][r] + bv[r], 0.f);
                *reinterpret_cast<f32x4*>((float*)outp + pixo + cb) = old;
            }
        }
    }
}

// ---------------------------------------------------------------------------
// Head conv as 256x256-tile LDS-staged GEMM (M=512 co, N=px, K=9*CIN tap-major).
// 512 thr, 8 waves x (128co x 64px), K-step 64, dbuf 128KB LDS, 2-phase sync.
// A tile: packed weights, swizzle pre-baked, linear global_load_lds.
// B tile: tap-shifted NHWC fp16 slab, per-lane src addr (inverse-swizzled),
//         zero-page redirect for image-edge halo. Epilogue bias+relu+mask.
// ---------------------------------------------------------------------------
template<int CIN>
__global__ __launch_bounds__(512, 1)
void gemm_head_kernel(const _Float16* __restrict__ in,
                      const _Float16* __restrict__ wpk,
                      const float* __restrict__ bias,
                      const int* __restrict__ fg,
                      _Float16* __restrict__ outp,
                      const _Float16* __restrict__ zpage)
{
    constexpr int SPT = CIN / 64;
    constexpr int NT = 9 * SPT;
    __shared__ _Float16 ldsh[65536];   // 128 KB: 2 bufs x (A 32KB + B 32KB)
    char* ldsb = (char*)ldsh;

    // bijective XCD swizzle: each XCD gets 64 consecutive wg = same (gy,img)
    const int wg = (blockIdx.x & 7) * 64 + (blockIdx.x >> 3);
    const int gy = wg >> 8;            // co-half
    const int img = (wg >> 6) & 3;
    const int tile = wg & 63;
    const int x0 = (tile & 7) << 4;
    const int y0 = (tile >> 3) << 4;

    const int tid = threadIdx.x;
    const int lane = tid & 63;
    const int wave = tid >> 6;
    const int lm = lane & 15;
    const int lu = lane >> 4;
    const int wco = (wave & 1) * 128;
    const int wpx = (wave >> 1) * 64;
    const int co0 = gy * 256;

    const _Float16* bsrc = in + (size_t)img * 16384 * CIN;

    auto STAGE = [&](int t, int bufByte) {
        const _Float16* as = wpk + (size_t)(t * 2 + gy) * 16384;
#pragma unroll
        for (int r = 0; r < 4; ++r)
            gll16(as + (size_t)(r * 512 + tid) * 8,
                  ldsb + bufByte + (r * 512 + (tid & ~63)) * 16);
        const int tap = t / SPT;
        const int ci0 = (t % SPT) * 64;
        const int dy = tap / 3 - 1, dx = tap % 3 - 1;
#pragma unroll
        for (int r = 0; r < 4; ++r) {
            const int prow = r * 64 + (tid >> 3);
            const int kc = (tid & 7) ^ (prow & 7);
            const int y = y0 + (prow >> 4) + dy;
            const int x = x0 + (prow & 15) + dx;
            const _Float16* src = ((unsigned)y < 128u && (unsigned)x < 128u)
                ? bsrc + (size_t)(y * 128 + x) * CIN + ci0 + kc * 8
                : zpage;
            gll16(src, ldsb + bufByte + 32768 + (r * 512 + (tid & ~63)) * 16);
        }
    };

    f32x4 acc[8][4];
#pragma unroll
    for (int m = 0; m < 8; ++m)
#pragma unroll
        for (int n = 0; n < 4; ++n)
            acc[m][n] = (f32x4){0.f, 0.f, 0.f, 0.f};

    STAGE(0, 0);
    __syncthreads();   // drains vmcnt(0) per HIP barrier semantics

    int bsel = 0;
    for (int t = 0; t < NT; ++t) {
        if (t + 1 < NT) STAGE(t + 1, (bsel ^ 1) * 65536);
        const int ab = bsel * 65536;
#pragma unroll
        for (int s = 0; s < 2; ++s) {
            f16x8 bfr[4];
#pragma unroll
            for (int n = 0; n < 4; ++n) {
                const int row = wpx + n * 16 + lm;
                const int ch = (s * 4 + lu) ^ (row & 7);
                bfr[n] = *reinterpret_cast<const f16x8*>(ldsb + ab + 32768 + row * 128 + ch * 16);
            }
#pragma unroll
            for (int m = 0; m < 8; ++m) {
                const int row = wco + m * 16 + lm;
                const int ch = (s * 4 + lu) ^ (row & 7);
                const f16x8 afr = *reinterpret_cast<const f16x8*>(ldsb + ab + row * 128 + ch * 16);
#pragma unroll
                for (int n = 0; n < 4; ++n)
                    acc[m][n] = __builtin_amdgcn_mfma_f32_16x16x32_f16(afr, bfr[n], acc[m][n], 0, 0, 0);
            }
        }
        __syncthreads();
        bsel ^= 1;
    }

    const int* mp = fg + img * 16384;
    _Float16* op = outp + (size_t)img * 16384 * 512;
#pragma unroll
    for (int n = 0; n < 4; ++n) {
        const int px = wpx + n * 16 + lm;
        const int y = y0 + (px >> 4), x = x0 + (px & 15);
        const float mv = (mp[y * 128 + x] > 0) ? 1.f : 0.f;
        _Float16* pp = op + (size_t)(y * 128 + x) * 512 + co0 + wco;
#pragma unroll
        for (int m = 0; m < 8; ++m) {
            const f32x4 bv = *reinterpret_cast<const f32x4*>(bias + co0 + wco + m * 16 + lu * 4);
            f16x4 h;
#pragma unroll
            for (int r = 0; r < 4; ++r)
                h[r] = (_Float16)(fmaxf(acc[m][n][r] + bv[r], 0.f) * mv);
            *reinterpret_cast<f16x4*>(pp + m * 16 + lu * 4) = h;
        }
    }
}

// ---------------------------------------------------------------------------
// fp16 NHWC 2x bilinear upsample (align_corners=False -> clamped 0.75/0.25).
// ---------------------------------------------------------------------------
__global__ void up2h_kernel(const _Float16* __restrict__ in, _Float16* __restrict__ out,
                            int Hin, int Win)
{
    const int Wout = Win << 1, Hout = Hin << 1;
    const int lw = __ffs(Wout) - 1, lh = __ffs(Hout) - 1;
    int i = blockIdx.x * THREADS + threadIdx.x;
    if (i >= 4 * Hout * Wout * 32) return;
    int u = i & 31;
    int p = i >> 5;
    int x = p & (Wout - 1);
    int y = (p >> lw) & (Hout - 1);
    int n = p >> (lw + lh);
    int iy = y >> 1, ix = x >> 1;
    int y2 = (y & 1) ? min(iy + 1, Hin - 1) : max(iy - 1, 0);
    int x2 = (x & 1) ? min(ix + 1, Win - 1) : max(ix - 1, 0);
    const _Float16* base = in + ((size_t)n * Hin * Win) * 256 + u * 8;
    f16x8 v00 = *reinterpret_cast<const f16x8*>(base + (iy * Win + ix) * 256);
    f16x8 v01 = *reinterpret_cast<const f16x8*>(base + (iy * Win + x2) * 256);
    f16x8 v10 = *reinterpret_cast<const f16x8*>(base + (y2 * Win + ix) * 256);
    f16x8 v11 = *reinterpret_cast<const f16x8*>(base + (y2 * Win + x2) * 256);
    f16x8 o;
#pragma unroll
    for (int j = 0; j < 8; ++j) {
        float v = 0.5625f * (float)v00[j] + 0.1875f * ((float)v01[j] + (float)v10[j])
                + 0.0625f * (float)v11[j];
        o[j] = (_Float16)v;
    }
    *reinterpret_cast<f16x8*>(out + (((size_t)n * Hout * Wout) + y * Wout + x) * 256 + u * 8) = o;
}

// fp32 NHWC 64^2 -> 128^2 upsample-ADD into Xc (stride 288, channels 0..255).
__global__ void up2add_kernel(const float* __restrict__ in, float* __restrict__ Xc)
{
    int i = blockIdx.x * THREADS + threadIdx.x;
    if (i >= 4 * 16384 * 32) return;
    int u = i & 31;
    int p = i >> 5;
    int x = p & 127;
    int y = (p >> 7) & 127;
    int n = p >> 14;
    int iy = y >> 1, ix = x >> 1;
    int y2 = (y & 1) ? min(iy + 1, 63) : max(iy - 1, 0);
    int x2 = (x & 1) ? min(ix + 1, 63) : max(ix - 1, 0);
    const float* base = in + ((size_t)n * 4096) * 256 + u * 8;
    f32x8 v00 = *reinterpret_cast<const f32x8*>(base + (iy * 64 + ix) * 256);
    f32x8 v01 = *reinterpret_cast<const f32x8*>(base + (iy * 64 + x2) * 256);
    f32x8 v10 = *reinterpret_cast<const f32x8*>(base + (y2 * 64 + ix) * 256);
    f32x8 v11 = *reinterpret_cast<const f32x8*>(base + (y2 * 64 + x2) * 256);
    float* dst = Xc + ((size_t)n * 16384 + y * 128 + x) * 288 + u * 8;
    f32x8 d = *reinterpret_cast<const f32x8*>(dst);
#pragma unroll
    for (int j = 0; j < 8; ++j)
        d[j] += 0.5625f * v00[j] + 0.1875f * (v01[j] + v10[j]) + 0.0625f * v11[j];
    *reinterpret_cast<f32x8*>(dst) = d;
}

// Coords into Xc channels 256..259; zero channels 260..287.
__global__ void coords2_kernel(const float* __restrict__ rel, const float* __restrict__ abs_,
                               float* __restrict__ Xc)
{
    int i = blockIdx.x * THREADS + threadIdx.x;
    if (i >= 4 * 16384) return;
    int px = i & 16383;
    int n = i >> 14;
    float* dst = Xc + ((size_t)n * 16384 + px) * 288 + 256;
    dst[0] = rel[((size_t)n * 2 + 0) * 16384 + px];
    dst[1] = rel[((size_t)n * 2 + 1) * 16384 + px];
    dst[2] = abs_[((size_t)n * 2 + 0) * 16384 + px];
    dst[3] = abs_[((size_t)n * 2 + 1) * 16384 + px];
#pragma unroll
    for (int c = 4; c < 32; ++c) dst[c] = 0.f;
}

// 1x1 predictor: NHWC fp16 [n][16384][512] -> NCHW fp32 [n][75][16384].
__global__ __launch_bounds__(256)
void predh_kernel(const _Float16* __restrict__ in, const float* __restrict__ w,
                  const float* __restrict__ bias, float* __restrict__ out)
{
    __shared__ _Float16 lw[25 * 512];
    const int co0 = blockIdx.y * 25;
    const int n = blockIdx.z;
    for (int idx = threadIdx.x; idx < 25 * 512; idx += 256)
        lw[idx] = (_Float16)w[(size_t)(co0 + idx / 512) * 512 + (idx & 511)];
    __syncthreads();
    int px = blockIdx.x * 256 + threadIdx.x;
    const _Float16* ip = in + ((size_t)n * 16384 + px) * 512;
    float acc[25];
#pragma unroll
    for (int j = 0; j < 25; ++j) acc[j] = bias[co0 + j];
    for (int g = 0; g < 64; ++g) {
        union { f16x8 v; f16x2 p[4]; } xv;
        xv.v = *reinterpret_cast<const f16x8*>(ip + g * 8);
#pragma unroll
        for (int j = 0; j < 25; ++j) {
            union { f16x8 v; f16x2 p[4]; } wv;
            wv.v = *reinterpret_cast<const f16x8*>(&lw[j * 512 + g * 8]);
#if __has_builtin(__builtin_amdgcn_fdot2)
#pragma unroll
            for (int k = 0; k < 4; ++k)
                acc[j] = __builtin_amdgcn_fdot2(xv.p[k], wv.p[k], acc[j], false);
#else
#pragma unroll
            for (int k = 0; k < 8; ++k)
                acc[j] = fmaf((float)xv.v[k], (float)wv.v[k], acc[j]);
#endif
        }
    }
    float* op = out + ((size_t)n * 75) * 16384 + px;
#pragma unroll
    for (int j = 0; j < 25; ++j)
        op[(size_t)(co0 + j) * 16384] = acc[j];
}

extern "C" void kernel_launch(void* const* d_in, const int* in_sizes, int n_in,
                              void* d_out, int out_size, void* d_ws, size_t ws_size,
                              hipStream_t stream)
{
    const float* p2   = (const float*)d_in[0];
    const float* p3   = (const float*)d_in[1];
    const float* p4   = (const float*)d_in[2];
    const float* p5   = (const float*)d_in[3];
    const float* rel  = (const float*)d_in[4];
    const float* abs_ = (const float*)d_in[5];
    const int*   fg   = (const int*)d_in[6];
    const float* w_p2_0 = (const float*)d_in[7];
    const float* b_p2_0 = (const float*)d_in[8];
    const float* w_p3_0 = (const float*)d_in[9];
    const float* b_p3_0 = (const float*)d_in[10];
    const float* w_p4_0 = (const float*)d_in[11];
    const float* b_p4_0 = (const float*)d_in[12];
    const float* w_p4_1 = (const float*)d_in[13];
    const float* b_p4_1 = (const float*)d_in[14];
    const float* w_p5_0 = (const float*)d_in[15];
    const float* b_p5_0 = (const float*)d_in[16];
    const float* w_p5_1 = (const float*)d_in[17];
    const float* b_p5_1 = (const float*)d_in[18];
    const float* w_p5_2 = (const float*)d_in[19];
    const float* b_p5_2 = (const float*)d_in[20];
    const float* comb_w = (const float*)d_in[21];
    const float* comb_b = (const float*)d_in[22];
    const float* head_w0 = (const float*)d_in[23];
    const float* head_b0 = (const float*)d_in[24];
    const float* head_w  = (const float*)d_in[25];
    const float* head_b  = (const float*)d_in[26];
    const float* pred_w  = (const float*)d_in[27];
    const float* pred_b  = (const float*)d_in[28];

    // Workspace layout (float offsets). Total ~57.1M floats = 228.4 MB.
    float* ws = (float*)d_ws;
    float*    Xc      = ws;                                  // 18,874,368
    _Float16* pingA   = (_Float16*)ws;                       // aliases Xc (dead after comb)
    _Float16* pingB   = (_Float16*)(ws + 18874368);          // 16,777,216
    float*    regD    = ws + 35651584;                       //  8,388,608
    _Float16* p2h     = (_Float16*)regD;
    _Float16* combOut = (_Float16*)regD;
    float*    t64sum  = regD;
    _Float16* t64b    = (_Float16*)(regD + 4194304);
    _Float16* t64c    = (_Float16*)(regD + 5242880);
    _Float16* t32a    = (_Float16*)(regD + 6291456);
    _Float16* t32b    = (_Float16*)(regD + 6553600);
    _Float16* t32c    = (_Float16*)(regD + 6815744);
    _Float16* t16a    = (_Float16*)(regD + 7077888);
    _Float16* p3h     = (_Float16*)(ws + 44040192);          //  2,097,152
    _Float16* p4h     = (_Float16*)(ws + 46137344);          //    524,288
    _Float16* p5h     = (_Float16*)(ws + 46661632);          //    131,072
    _Float16* wpScale = (_Float16*)(ws + 46792704);          //  1,441,792
    float*    zpage   = ws + 48234496;                       //      1,024 (4 KB zeros)
    _Float16* wpH0    = (_Float16*)(ws + 48235520);          //    589,824 (1,179,648 f16)
    _Float16* wpH     = (_Float16*)(ws + 48825344);          //  8,257,536 (7 x 2,359,296 f16)

    auto packw = [&](const float* w, _Float16* dst, int Cin, int Cout) {
        int CCl = (Cin + 31) / 32;
        int total = Cout * CCl * 4;
        pack_w16_kernel<<<dim3((total + THREADS - 1) / THREADS), dim3(THREADS), 0, stream>>>(
            w, dst, Cin, Cout, CCl);
    };
    auto transp = [&](const float* in, _Float16* out, int C, int HW) {
        t_kernel<<<dim3(HW / 64, C / 32, 4), dim3(256), 0, stream>>>(in, out, C, HW);
    };
    auto convu = [&](const void* in, const _Float16* wpk, const float* bs, void* outp,
                     int inf32, int outmode, int Cout, int H, int W,
                     int inCst, int outCst, int useMask) {
        dim3 grid((W / 16) * (H / 16), Cout / 128, 4);
        dim3 blk(512);
        if (inf32 == 0 && outmode == 0)
            convu_kernel<0, 0, 8><<<grid, blk, 0, stream>>>(in, wpk, bs, fg, outp, Cout, H, W, inCst, outCst, useMask);
        else if (inf32 == 0 && outmode == 1)
            convu_kernel<0, 1, 8><<<grid, blk, 0, stream>>>(in, wpk, bs, fg, outp, Cout, H, W, inCst, outCst, useMask);
        else if (inf32 == 0 && outmode == 2)
            convu_kernel<0, 2, 8><<<grid, blk, 0, stream>>>(in, wpk, bs, fg, outp, Cout, H, W, inCst, outCst, useMask);
        else
            convu_kernel<1, 0, 9><<<grid, blk, 0, stream>>>(in, wpk, bs, fg, outp, Cout, H, W, inCst, outCst, useMask);
    };
    auto up2h = [&](const _Float16* in, _Float16* out, int Hin, int Win) {
        int total = 4 * (Hin * 2) * (Win * 2) * 32;
        up2h_kernel<<<dim3((total + THREADS - 1) / THREADS), dim3(THREADS), 0, stream>>>(
            in, out, Hin, Win);
    };

    // ---- zero-page + pack head weights (GEMM format, persistent) ----
    zerows_kernel<<<dim3(4), dim3(THREADS), 0, stream>>>(zpage);
    pack_whead_kernel<<<dim3(576), dim3(THREADS), 0, stream>>>(head_w0, wpH0, 256);
    for (int i = 0; i < 7; ++i)
        pack_whead_kernel<<<dim3(1152), dim3(THREADS), 0, stream>>>(
            head_w + (size_t)i * 2359296, wpH + (size_t)i * 2359296, 512);

    // ---- transpose FPN inputs to NHWC fp16 ----
    transp(p2, p2h, 256, 16384);
    transp(p3, p3h, 256, 4096);
    transp(p4, p4h, 256, 1024);
    transp(p5, p5h, 256, 256);

    // ---- p2 scale head -> Xc (fp32 NHWC-288), coords+zeropad ----
    packw(w_p2_0, wpScale, 256, 256);
    convu(p2h, wpScale, b_p2_0, Xc, 0, 1, 256, 128, 128, 256, 288, 0);
    coords2_kernel<<<dim3(256), dim3(THREADS), 0, stream>>>(rel, abs_, Xc);

    // ---- p3 -> t64sum (write) ----
    packw(w_p3_0, wpScale, 256, 256);
    convu(p3h, wpScale, b_p3_0, t64sum, 0, 1, 256, 64, 64, 256, 256, 0);

    // ---- p4 chain: conv32 -> up -> conv64 (add into t64sum) ----
    packw(w_p4_0, wpScale, 256, 256);
    convu(p4h, wpScale, b_p4_0, t32a, 0, 0, 256, 32, 32, 256, 256, 0);
    up2h(t32a, t64b, 32, 32);
    packw(w_p4_1, wpScale, 256, 256);
    convu(t64b, wpScale, b_p4_1, t64sum, 0, 2, 256, 64, 64, 256, 256, 0);

    // ---- p5 chain: conv16 -> up -> conv32 -> up -> conv64 (add) ----
    packw(w_p5_0, wpScale, 256, 256);
    convu(p5h, wpScale, b_p5_0, t16a, 0, 0, 256, 16, 16, 256, 256, 0);
    up2h(t16a, t32b, 16, 16);
    packw(w_p5_1, wpScale, 256, 256);
    convu(t32b, wpScale, b_p5_1, t32c, 0, 0, 256, 32, 32, 256, 256, 0);
    up2h(t32c, t64c, 32, 32);
    packw(w_p5_2, wpScale, 256, 256);
    convu(t64c, wpScale, b_p5_2, t64sum, 0, 2, 256, 64, 64, 256, 256, 0);

    // ---- single upsample-add of merged 64^2 sum into Xc ----
    up2add_kernel<<<dim3(8192), dim3(THREADS), 0, stream>>>(t64sum, Xc);

    // ---- comb conv (Xc fp32 NHWC-288 -> combOut fp16 NHWC-256), relu+mask ----
    packw(comb_w, wpScale, 260, 256);
    convu(Xc, wpScale, comb_b, combOut, 1, 0, 256, 128, 128, 288, 256, 1);

    // ---- head chain: 256^2-tile LDS-staged GEMM convs, batched ----
    gemm_head_kernel<256><<<dim3(512), dim3(512), 0, stream>>>(
        combOut, wpH0, head_b0, fg, pingA, (const _Float16*)zpage);
    {
        const _Float16* s = pingA;
        _Float16* d = pingB;
        for (int i = 0; i < 7; ++i) {
            gemm_head_kernel<512><<<dim3(512), dim3(512), 0, stream>>>(
                s, wpH + (size_t)i * 2359296, head_b + (size_t)i * 512, fg, d,
                (const _Float16*)zpage);
            _Float16* tmp = (_Float16*)s; s = d; d = tmp;
        }
    }

    // ---- predictor (reads pingB), batched ----
    predh_kernel<<<dim3(64, 3, 4), dim3(256), 0, stream>>>(pingB, pred_w, pred_b, (float*)d_out);
}

// Round 6
// 3015.964 us; speedup vs baseline: 19.4683x; 1.0529x over previous
//
#include <hip/hip_runtime.h>
#include <cstdint>
#include <cstddef>

#define THREADS 256

typedef _Float16 f16x8 __attribute__((ext_vector_type(8)));
typedef _Float16 f16x4 __attribute__((ext_vector_type(4)));
typedef _Float16 f16x2 __attribute__((ext_vector_type(2)));
typedef float f32x4 __attribute__((ext_vector_type(4)));
typedef float f32x8 __attribute__((ext_vector_type(8)));

__device__ __forceinline__ void gll16(const void* g, void* l) {
    __builtin_amdgcn_global_load_lds(
        (const __attribute__((address_space(1))) unsigned int*)g,
        (__attribute__((address_space(3))) unsigned int*)l, 16, 0, 0);
}

// ---------------------------------------------------------------------------
// Weight pack (old format, for scale/comb convs):
// fp32 OIHW -> fp16 [tap][cc][u(4)][co][8]  (zero-fill ci>=Cin)
// ---------------------------------------------------------------------------
__global__ void pack_w16_kernel(const float* __restrict__ w, _Float16* __restrict__ wp,
                                int Cin, int Cout, int CC)
{
    int idx = blockIdx.x * THREADS + threadIdx.x;
    int total = Cout * CC * 4;
    if (idx >= total) return;
    int u = idx & 3;
    int cc = (idx >> 2) % CC;
    int co = (idx >> 2) / CC;
    int ci0 = cc * 32 + u * 8;
    for (int tap = 0; tap < 9; ++tap) {
        f16x8 v;
#pragma unroll
        for (int j = 0; j < 8; ++j) {
            int ci = ci0 + j;
            v[j] = (ci < Cin) ? (_Float16)w[((size_t)co * Cin + ci) * 9 + tap] : (_Float16)0.f;
        }
        *reinterpret_cast<f16x8*>(wp + ((((size_t)tap * CC + cc) * 4 + u) * Cout + co) * 8) = v;
    }
}

// ---------------------------------------------------------------------------
// Head-GEMM weight pack: fp32 OIHW -> fp16 [kstep][gy(2)][chunk 2048][8]
// K linearized tap-major (k = tap*Cin + ci), 64-wide K-steps.
// Bank-swizzle baked in: chunk (r*8+kc) holds k-slice (kc ^ (r&7)).
// ---------------------------------------------------------------------------
__global__ void pack_whead_kernel(const float* __restrict__ w, _Float16* __restrict__ wp,
                                  int Cin)
{
    const int NSTEP = 9 * (Cin / 64);
    int idx = blockIdx.x * THREADS + threadIdx.x;
    int total = 512 * NSTEP * 8;
    if (idx >= total) return;
    int kc = idx & 7;
    int t = (idx >> 3) % NSTEP;
    int co = (idx >> 3) / NSTEP;
    int gy = co >> 8;
    int r = co & 255;
    int kcs = kc ^ (r & 7);
    int k = t * 64 + kcs * 8;
    int tap = k / Cin;
    int cib = k - tap * Cin;
    f16x8 v;
#pragma unroll
    for (int j = 0; j < 8; ++j)
        v[j] = (_Float16)w[((size_t)co * Cin + cib + j) * 9 + tap];
    *reinterpret_cast<f16x8*>(wp + ((size_t)(t * 2 + gy) * 2048 + r * 8 + kc) * 8) = v;
}

__global__ void zerows_kernel(float* __restrict__ p)
{
    p[blockIdx.x * THREADS + threadIdx.x] = 0.f;
}

// ---------------------------------------------------------------------------
// NCHW fp32 -> NHWC fp16 transpose. Tile: 32 ci x 64 px. Grid (HW/64, C/32, N).
// ---------------------------------------------------------------------------
__global__ __launch_bounds__(256)
void t_kernel(const float* __restrict__ in, _Float16* __restrict__ out, int C, int HW)
{
    __shared__ _Float16 tile[64 * 32];
    const int n = blockIdx.z;
    const int c0 = blockIdx.y * 32;
    const int p0 = blockIdx.x * 64;
    const int tid = threadIdx.x;
    {
        int ci = tid >> 3;
        int j8 = (tid & 7) * 8;
        f32x8 v = *reinterpret_cast<const f32x8*>(in + ((size_t)n * C + c0 + ci) * HW + p0 + j8);
#pragma unroll
        for (int j = 0; j < 8; ++j)
            tile[(j8 + j) * 32 + ci] = (_Float16)v[j];
    }
    __syncthreads();
    {
        int px = tid >> 2;
        int u = tid & 3;
        f16x8 v = *reinterpret_cast<const f16x8*>(&tile[px * 32 + u * 8]);
        *reinterpret_cast<f16x8*>(out + ((size_t)n * HW + p0 + px) * C + c0 + u * 8) = v;
    }
}

// ---------------------------------------------------------------------------
// Old unified conv (kept for scale heads + comb conv). See round-4 comments.
// ---------------------------------------------------------------------------
template<int INF32, int OUTMODE, int CC>
__global__ __launch_bounds__(512, 4)
void convu_kernel(const void* __restrict__ inv, const _Float16* __restrict__ wp,
                  const float* __restrict__ bias, const int* __restrict__ msk,
                  void* __restrict__ outp, int Cout, int H, int W,
                  int inCst, int outCst, int useMask)
{
    __shared__ _Float16 Xs[2 * 1344 * 8];

    const int tid = threadIdx.x;
    const int lane = tid & 63;
    const int wave = tid >> 6;
    const int lm = lane & 15;
    const int lu = lane >> 4;
    const int waveco = (wave & 1) * 64;
    const int wrow = (wave >> 1) * 4;
    const int n = blockIdx.z;
    const int co0 = blockIdx.y * 128;
    const int tpr = W >> 4;
    const int tx = blockIdx.x % tpr;
    const int ty = blockIdx.x / tpr;
    const int x0 = tx << 4;
    const int y0 = ty << 4;
    const int HW = H * W;

    int soff[3];
#pragma unroll
    for (int t = 0; t < 3; ++t) {
        int s = tid + t * 512;
        int item = s >> 2, u = s & 3;
        int row = item / 18, col = item - row * 18;
        int y = y0 + row - 1, x = x0 + col - 1;
        soff[t] = (s < 1296 && y >= 0 && y < H && x >= 0 && x < W)
                      ? ((n * HW + y * W + x) * inCst + u * 8) : -1;
    }

    f32x4 acc[4][4];
#pragma unroll
    for (int m = 0; m < 4; ++m)
#pragma unroll
        for (int nf = 0; nf < 4; ++nf)
            acc[m][nf] = (f32x4){0.f, 0.f, 0.f, 0.f};

    const size_t tstride = (size_t)CC * 4 * Cout * 8;
    f32x8 rr[3];

    if (INF32 == 0) {
        const _Float16* src = (const _Float16*)inv;
#pragma unroll
        for (int t = 0; t < 3; ++t) {
            int s = tid + t * 512;
            if (s < 1296 && soff[t] < 0) {
                *reinterpret_cast<f16x8*>(&Xs[s * 8]) = (f16x8){};
                *reinterpret_cast<f16x8*>(&Xs[(1344 + s) * 8]) = (f16x8){};
            }
        }
#pragma unroll
        for (int t = 0; t < 3; ++t) {
            int s = tid + t * 512;
            if (s < 1296 && soff[t] >= 0)
                gll16(src + soff[t], &Xs[(t * 512 + (tid & ~63)) * 8]);
        }
    } else {
        const float* srcf = (const float*)inv;
#pragma unroll
        for (int t = 0; t < 3; ++t) {
            int s = tid + t * 512;
            rr[t] = (f32x8){};
            if (s < 1296 && soff[t] >= 0)
                rr[t] = *reinterpret_cast<const f32x8*>(srcf + soff[t]);
        }
#pragma unroll
        for (int t = 0; t < 3; ++t) {
            int s = tid + t * 512;
            if (s < 1296) {
                f16x8 h;
#pragma unroll
                for (int j = 0; j < 8; ++j) h[j] = (_Float16)rr[t][j];
                *reinterpret_cast<f16x8*>(&Xs[s * 8]) = h;
            }
        }
    }
    __syncthreads();

    int bsel = 0;
    for (int cc = 0; cc < CC; ++cc) {
        if (cc + 1 < CC) {
            if (INF32 == 0) {
                const _Float16* src = (const _Float16*)inv;
#pragma unroll
                for (int t = 0; t < 3; ++t) {
                    int s = tid + t * 512;
                    if (s < 1296 && soff[t] >= 0)
                        gll16(src + soff[t] + (cc + 1) * 32,
                              &Xs[((bsel ^ 1) * 1344 + t * 512 + (tid & ~63)) * 8]);
                }
            } else {
                const float* srcf = (const float*)inv;
#pragma unroll
                for (int t = 0; t < 3; ++t) {
                    int s = tid + t * 512;
                    rr[t] = (f32x8){};
                    if (s < 1296 && soff[t] >= 0)
                        rr[t] = *reinterpret_cast<const f32x8*>(srcf + soff[t] + (cc + 1) * 32);
                }
            }
        }
        {
            const int xbase = bsel * 1344;
            const _Float16* wb = wp + (((size_t)cc * 4 + lu) * Cout + co0 + waveco + lm) * 8;
#pragma unroll
            for (int tap = 0; tap < 9; ++tap) {
                const int dy = tap / 3, dx = tap % 3;
                const _Float16* wt = wb + (size_t)tap * tstride;
                f16x8 a[4], b[4];
#pragma unroll
                for (int m = 0; m < 4; ++m)
                    a[m] = *reinterpret_cast<const f16x8*>(wt + m * 128);
#pragma unroll
                for (int nf = 0; nf < 4; ++nf) {
                    int slot = ((wrow + nf + dy) * 18 + lm + dx) * 4 + lu;
                    b[nf] = *reinterpret_cast<const f16x8*>(&Xs[(xbase + slot) * 8]);
                }
#pragma unroll
                for (int m = 0; m < 4; ++m)
#pragma unroll
                    for (int nf = 0; nf < 4; ++nf)
                        acc[m][nf] = __builtin_amdgcn_mfma_f32_16x16x32_f16(a[m], b[nf], acc[m][nf], 0, 0, 0);
            }
        }
        if (INF32 == 1 && cc + 1 < CC) {
#pragma unroll
            for (int t = 0; t < 3; ++t) {
                int s = tid + t * 512;
                if (s < 1296) {
                    f16x8 h;
#pragma unroll
                    for (int j = 0; j < 8; ++j) h[j] = (_Float16)rr[t][j];
                    *reinterpret_cast<f16x8*>(&Xs[((bsel ^ 1) * 1344 + s) * 8]) = h;
                }
            }
        }
        __syncthreads();
        bsel ^= 1;
    }

    const int xE = x0 + lm;
    const size_t nHW = (size_t)n * HW;
#pragma unroll
    for (int nf = 0; nf < 4; ++nf) {
        const int y = y0 + wrow + nf;
        float mv = 1.f;
        if (useMask) mv = (msk[nHW + y * W + xE] > 0) ? 1.f : 0.f;
        const size_t pixo = (nHW + (size_t)y * W + xE) * outCst;
#pragma unroll
        for (int m = 0; m < 4; ++m) {
            const int cb = co0 + waveco + m * 16 + lu * 4;
            const f32x4 bv = *reinterpret_cast<const f32x4*>(bias + cb);
            if (OUTMODE == 0) {
                f16x4 h;
#pragma unroll
                for (int r = 0; r < 4; ++r)
                    h[r] = (_Float16)(fmaxf(acc[m][nf][r] + bv[r], 0.f) * mv);
                *reinterpret_cast<f16x4*>((_Float16*)outp + pixo + cb) = h;
            } else if (OUTMODE == 1) {
                f32x4 v;
#pragma unroll
                for (int r = 0; r < 4; ++r)
                    v[r] = fmaxf(acc[m][nf][r] + bv[r], 0.f);
                *reinterpret_cast<f32x4*>((float*)outp + pixo + cb) = v;
            } else {
                f32x4 old = *reinterpret_cast<const f32x4*>((float*)outp + pixo + cb);
#pragma unroll
                for (int r = 0; r < 4; ++r)
                    old[r] += fmaxf(acc[m][nf][r] + bv[r], 0.f);
                *reinterpret_cast<f32x4*>((float*)outp + pixo + cb) = old;
            }
        }
    }
}

// ---------------------------------------------------------------------------
// Head conv as 256x256-tile LDS-staged GEMM (M=512 co, N=px, K=9*CIN).
// 512 thr, 8 waves x (128co x 64px), K-step 64, dbuf 128KB LDS, 2-phase sync.
// R6 changes vs R5:
//  (a) K-loop is ci-block-major (cb outer, tap inner): the same activation
//      lines are re-read at 9 CONSECUTIVE steps -> L2-hot (was tap-major,
//      9 re-fetches from L3; FETCH_SIZE 602 MB/dispatch).
//  (b) XCD remap co-locates both co-halves (gy) of a tile on one XCD:
//      XCD = (img, image-half); r = tile*2 + gy. B distinct/XCD 32->10.6 MB.
// ---------------------------------------------------------------------------
template<int CIN>
__global__ __launch_bounds__(512, 1)
void gemm_head_kernel(const _Float16* __restrict__ in,
                      const _Float16* __restrict__ wpk,
                      const float* __restrict__ bias,
                      const int* __restrict__ fg,
                      _Float16* __restrict__ outp,
                      const _Float16* __restrict__ zpage)
{
    constexpr int SPT = CIN / 64;
    __shared__ _Float16 ldsh[65536];   // 128 KB: 2 bufs x (A 32KB + B 32KB)
    char* ldsb = (char*)ldsh;

    // XCD remap: b&7 ~ XCD; each XCD gets both gy of 32 tiles of one image.
    const int b = blockIdx.x;
    const int xcd = b & 7;
    const int r = b >> 3;              // 0..63
    const int img = xcd >> 1;          // 0..3
    const int half = xcd & 1;          // image half (tile rows 0-3 / 4-7)
    const int tile = half * 32 + (r >> 1);
    const int gy = r & 1;
    const int x0 = (tile & 7) << 4;
    const int y0 = (tile >> 3) << 4;

    const int tid = threadIdx.x;
    const int lane = tid & 63;
    const int wave = tid >> 6;
    const int lm = lane & 15;
    const int lu = lane >> 4;
    const int wco = (wave & 1) * 128;
    const int wpx = (wave >> 1) * 64;
    const int co0 = gy * 256;

    const _Float16* bsrc = in + (size_t)img * 16384 * CIN;

    auto STAGE = [&](int t, int bufByte) {
        const _Float16* as = wpk + (size_t)(t * 2 + gy) * 16384;
#pragma unroll
        for (int rr = 0; rr < 4; ++rr)
            gll16(as + (size_t)(rr * 512 + tid) * 8,
                  ldsb + bufByte + (rr * 512 + (tid & ~63)) * 16);
        const int tap = t / SPT;
        const int ci0 = (t % SPT) * 64;
        const int dy = tap / 3 - 1, dx = tap % 3 - 1;
#pragma unroll
        for (int rr = 0; rr < 4; ++rr) {
            const int prow = rr * 64 + (tid >> 3);
            const int kc = (tid & 7) ^ (prow & 7);
            const int y = y0 + (prow >> 4) + dy;
            const int x = x0 + (prow & 15) + dx;
            const _Float16* src = ((unsigned)y < 128u && (unsigned)x < 128u)
                ? bsrc + (size_t)(y * 128 + x) * CIN + ci0 + kc * 8
                : zpage;
            gll16(src, ldsb + bufByte + 32768 + (rr * 512 + (tid & ~63)) * 16);
        }
    };

    f32x4 acc[8][4];
#pragma unroll
    for (int m = 0; m < 8; ++m)
#pragma unroll
        for (int n = 0; n < 4; ++n)
            acc[m][n] = (f32x4){0.f, 0.f, 0.f, 0.f};

    STAGE(0, 0);
    __syncthreads();   // drains vmcnt(0) per HIP barrier semantics

    int bsel = 0;
    for (int cb = 0; cb < SPT; ++cb) {
        for (int tap = 0; tap < 9; ++tap) {
            if (tap < 8) STAGE((tap + 1) * SPT + cb, (bsel ^ 1) * 65536);
            else if (cb + 1 < SPT) STAGE(cb + 1, (bsel ^ 1) * 65536);
            const int ab = bsel * 65536;
#pragma unroll
            for (int s = 0; s < 2; ++s) {
                f16x8 bfr[4];
#pragma unroll
                for (int n = 0; n < 4; ++n) {
                    const int row = wpx + n * 16 + lm;
                    const int ch = (s * 4 + lu) ^ (row & 7);
                    bfr[n] = *reinterpret_cast<const f16x8*>(ldsb + ab + 32768 + row * 128 + ch * 16);
                }
#pragma unroll
                for (int m = 0; m < 8; ++m) {
                    const int row = wco + m * 16 + lm;
                    const int ch = (s * 4 + lu) ^ (row & 7);
                    const f16x8 afr = *reinterpret_cast<const f16x8*>(ldsb + ab + row * 128 + ch * 16);
#pragma unroll
                    for (int n = 0; n < 4; ++n)
                        acc[m][n] = __builtin_amdgcn_mfma_f32_16x16x32_f16(afr, bfr[n], acc[m][n], 0, 0, 0);
                }
            }
            __syncthreads();
            bsel ^= 1;
        }
    }

    const int* mp = fg + img * 16384;
    _Float16* op = outp + (size_t)img * 16384 * 512;
#pragma unroll
    for (int n = 0; n < 4; ++n) {
        const int px = wpx + n * 16 + lm;
        const int y = y0 + (px >> 4), x = x0 + (px & 15);
        const float mv = (mp[y * 128 + x] > 0) ? 1.f : 0.f;
        _Float16* pp = op + (size_t)(y * 128 + x) * 512 + co0 + wco;
#pragma unroll
        for (int m = 0; m < 8; ++m) {
            const f32x4 bv = *reinterpret_cast<const f32x4*>(bias + co0 + wco + m * 16 + lu * 4);
            f16x4 h;
#pragma unroll
            for (int rr = 0; rr < 4; ++rr)
                h[rr] = (_Float16)(fmaxf(acc[m][n][rr] + bv[rr], 0.f) * mv);
            *reinterpret_cast<f16x4*>(pp + m * 16 + lu * 4) = h;
        }
    }
}

// ---------------------------------------------------------------------------
// fp16 NHWC 2x bilinear upsample (align_corners=False -> clamped 0.75/0.25).
// ---------------------------------------------------------------------------
__global__ void up2h_kernel(const _Float16* __restrict__ in, _Float16* __restrict__ out,
                            int Hin, int Win)
{
    const int Wout = Win << 1, Hout = Hin << 1;
    const int lw = __ffs(Wout) - 1, lh = __ffs(Hout) - 1;
    int i = blockIdx.x * THREADS + threadIdx.x;
    if (i >= 4 * Hout * Wout * 32) return;
    int u = i & 31;
    int p = i >> 5;
    int x = p & (Wout - 1);
    int y = (p >> lw) & (Hout - 1);
    int n = p >> (lw + lh);
    int iy = y >> 1, ix = x >> 1;
    int y2 = (y & 1) ? min(iy + 1, Hin - 1) : max(iy - 1, 0);
    int x2 = (x & 1) ? min(ix + 1, Win - 1) : max(ix - 1, 0);
    const _Float16* base = in + ((size_t)n * Hin * Win) * 256 + u * 8;
    f16x8 v00 = *reinterpret_cast<const f16x8*>(base + (iy * Win + ix) * 256);
    f16x8 v01 = *reinterpret_cast<const f16x8*>(base + (iy * Win + x2) * 256);
    f16x8 v10 = *reinterpret_cast<const f16x8*>(base + (y2 * Win + ix) * 256);
    f16x8 v11 = *reinterpret_cast<const f16x8*>(base + (y2 * Win + x2) * 256);
    f16x8 o;
#pragma unroll
    for (int j = 0; j < 8; ++j) {
        float v = 0.5625f * (float)v00[j] + 0.1875f * ((float)v01[j] + (float)v10[j])
                + 0.0625f * (float)v11[j];
        o[j] = (_Float16)v;
    }
    *reinterpret_cast<f16x8*>(out + (((size_t)n * Hout * Wout) + y * Wout + x) * 256 + u * 8) = o;
}

// fp32 NHWC 64^2 -> 128^2 upsample-ADD into Xc (stride 288, channels 0..255).
__global__ void up2add_kernel(const float* __restrict__ in, float* __restrict__ Xc)
{
    int i = blockIdx.x * THREADS + threadIdx.x;
    if (i >= 4 * 16384 * 32) return;
    int u = i & 31;
    int p = i >> 5;
    int x = p & 127;
    int y = (p >> 7) & 127;
    int n = p >> 14;
    int iy = y >> 1, ix = x >> 1;
    int y2 = (y & 1) ? min(iy + 1, 63) : max(iy - 1, 0);
    int x2 = (x & 1) ? min(ix + 1, 63) : max(ix - 1, 0);
    const float* base = in + ((size_t)n * 4096) * 256 + u * 8;
    f32x8 v00 = *reinterpret_cast<const f32x8*>(base + (iy * 64 + ix) * 256);
    f32x8 v01 = *reinterpret_cast<const f32x8*>(base + (iy * 64 + x2) * 256);
    f32x8 v10 = *reinterpret_cast<const f32x8*>(base + (y2 * 64 + ix) * 256);
    f32x8 v11 = *reinterpret_cast<const f32x8*>(base + (y2 * 64 + x2) * 256);
    float* dst = Xc + ((size_t)n * 16384 + y * 128 + x) * 288 + u * 8;
    f32x8 d = *reinterpret_cast<const f32x8*>(dst);
#pragma unroll
    for (int j = 0; j < 8; ++j)
        d[j] += 0.5625f * v00[j] + 0.1875f * (v01[j] + v10[j]) + 0.0625f * v11[j];
    *reinterpret_cast<f32x8*>(dst) = d;
}

// Coords into Xc channels 256..259; zero channels 260..287.
__global__ void coords2_kernel(const float* __restrict__ rel, const float* __restrict__ abs_,
                               float* __restrict__ Xc)
{
    int i = blockIdx.x * THREADS + threadIdx.x;
    if (i >= 4 * 16384) return;
    int px = i & 16383;
    int n = i >> 14;
    float* dst = Xc + ((size_t)n * 16384 + px) * 288 + 256;
    dst[0] = rel[((size_t)n * 2 + 0) * 16384 + px];
    dst[1] = rel[((size_t)n * 2 + 1) * 16384 + px];
    dst[2] = abs_[((size_t)n * 2 + 0) * 16384 + px];
    dst[3] = abs_[((size_t)n * 2 + 1) * 16384 + px];
#pragma unroll
    for (int c = 4; c < 32; ++c) dst[c] = 0.f;
}

// 1x1 predictor: NHWC fp16 [n][16384][512] -> NCHW fp32 [n][75][16384].
__global__ __launch_bounds__(256)
void predh_kernel(const _Float16* __restrict__ in, const float* __restrict__ w,
                  const float* __restrict__ bias, float* __restrict__ out)
{
    __shared__ _Float16 lw[25 * 512];
    const int co0 = blockIdx.y * 25;
    const int n = blockIdx.z;
    for (int idx = threadIdx.x; idx < 25 * 512; idx += 256)
        lw[idx] = (_Float16)w[(size_t)(co0 + idx / 512) * 512 + (idx & 511)];
    __syncthreads();
    int px = blockIdx.x * 256 + threadIdx.x;
    const _Float16* ip = in + ((size_t)n * 16384 + px) * 512;
    float acc[25];
#pragma unroll
    for (int j = 0; j < 25; ++j) acc[j] = bias[co0 + j];
    for (int g = 0; g < 64; ++g) {
        union { f16x8 v; f16x2 p[4]; } xv;
        xv.v = *reinterpret_cast<const f16x8*>(ip + g * 8);
#pragma unroll
        for (int j = 0; j < 25; ++j) {
            union { f16x8 v; f16x2 p[4]; } wv;
            wv.v = *reinterpret_cast<const f16x8*>(&lw[j * 512 + g * 8]);
#if __has_builtin(__builtin_amdgcn_fdot2)
#pragma unroll
            for (int k = 0; k < 4; ++k)
                acc[j] = __builtin_amdgcn_fdot2(xv.p[k], wv.p[k], acc[j], false);
#else
#pragma unroll
            for (int k = 0; k < 8; ++k)
                acc[j] = fmaf((float)xv.v[k], (float)wv.v[k], acc[j]);
#endif
        }
    }
    float* op = out + ((size_t)n * 75) * 16384 + px;
#pragma unroll
    for (int j = 0; j < 25; ++j)
        op[(size_t)(co0 + j) * 16384] = acc[j];
}

extern "C" void kernel_launch(void* const* d_in, const int* in_sizes, int n_in,
                              void* d_out, int out_size, void* d_ws, size_t ws_size,
                              hipStream_t stream)
{
    const float* p2   = (const float*)d_in[0];
    const float* p3   = (const float*)d_in[1];
    const float* p4   = (const float*)d_in[2];
    const float* p5   = (const float*)d_in[3];
    const float* rel  = (const float*)d_in[4];
    const float* abs_ = (const float*)d_in[5];
    const int*   fg   = (const int*)d_in[6];
    const float* w_p2_0 = (const float*)d_in[7];
    const float* b_p2_0 = (const float*)d_in[8];
    const float* w_p3_0 = (const float*)d_in[9];
    const float* b_p3_0 = (const float*)d_in[10];
    const float* w_p4_0 = (const float*)d_in[11];
    const float* b_p4_0 = (const float*)d_in[12];
    const float* w_p4_1 = (const float*)d_in[13];
    const float* b_p4_1 = (const float*)d_in[14];
    const float* w_p5_0 = (const float*)d_in[15];
    const float* b_p5_0 = (const float*)d_in[16];
    const float* w_p5_1 = (const float*)d_in[17];
    const float* b_p5_1 = (const float*)d_in[18];
    const float* w_p5_2 = (const float*)d_in[19];
    const float* b_p5_2 = (const float*)d_in[20];
    const float* comb_w = (const float*)d_in[21];
    const float* comb_b = (const float*)d_in[22];
    const float* head_w0 = (const float*)d_in[23];
    const float* head_b0 = (const float*)d_in[24];
    const float* head_w  = (const float*)d_in[25];
    const float* head_b  = (const float*)d_in[26];
    const float* pred_w  = (const float*)d_in[27];
    const float* pred_b  = (const float*)d_in[28];

    // Workspace layout (float offsets). Total ~57.1M floats = 228.4 MB.
    float* ws = (float*)d_ws;
    float*    Xc      = ws;                                  // 18,874,368
    _Float16* pingA   = (_Float16*)ws;                       // aliases Xc (dead after comb)
    _Float16* pingB   = (_Float16*)(ws + 18874368);          // 16,777,216
    float*    regD    = ws + 35651584;                       //  8,388,608
    _Float16* p2h     = (_Float16*)regD;
    _Float16* combOut = (_Float16*)regD;
    float*    t64sum  = regD;
    _Float16* t64b    = (_Float16*)(regD + 4194304);
    _Float16* t64c    = (_Float16*)(regD + 5242880);
    _Float16* t32a    = (_Float16*)(regD + 6291456);
    _Float16* t32b    = (_Float16*)(regD + 6553600);
    _Float16* t32c    = (_Float16*)(regD + 6815744);
    _Float16* t16a    = (_Float16*)(regD + 7077888);
    _Float16* p3h     = (_Float16*)(ws + 44040192);          //  2,097,152
    _Float16* p4h     = (_Float16*)(ws + 46137344);          //    524,288
    _Float16* p5h     = (_Float16*)(ws + 46661632);          //    131,072
    _Float16* wpScale = (_Float16*)(ws + 46792704);          //  1,441,792
    float*    zpage   = ws + 48234496;                       //      1,024 (4 KB zeros)
    _Float16* wpH0    = (_Float16*)(ws + 48235520);          //    589,824 (1,179,648 f16)
    _Float16* wpH     = (_Float16*)(ws + 48825344);          //  8,257,536 (7 x 2,359,296 f16)

    auto packw = [&](const float* w, _Float16* dst, int Cin, int Cout) {
        int CCl = (Cin + 31) / 32;
        int total = Cout * CCl * 4;
        pack_w16_kernel<<<dim3((total + THREADS - 1) / THREADS), dim3(THREADS), 0, stream>>>(
            w, dst, Cin, Cout, CCl);
    };
    auto transp = [&](const float* in, _Float16* out, int C, int HW) {
        t_kernel<<<dim3(HW / 64, C / 32, 4), dim3(256), 0, stream>>>(in, out, C, HW);
    };
    auto convu = [&](const void* in, const _Float16* wpk, const float* bs, void* outp,
                     int inf32, int outmode, int Cout, int H, int W,
                     int inCst, int outCst, int useMask) {
        dim3 grid((W / 16) * (H / 16), Cout / 128, 4);
        dim3 blk(512);
        if (inf32 == 0 && outmode == 0)
            convu_kernel<0, 0, 8><<<grid, blk, 0, stream>>>(in, wpk, bs, fg, outp, Cout, H, W, inCst, outCst, useMask);
        else if (inf32 == 0 && outmode == 1)
            convu_kernel<0, 1, 8><<<grid, blk, 0, stream>>>(in, wpk, bs, fg, outp, Cout, H, W, inCst, outCst, useMask);
        else if (inf32 == 0 && outmode == 2)
            convu_kernel<0, 2, 8><<<grid, blk, 0, stream>>>(in, wpk, bs, fg, outp, Cout, H, W, inCst, outCst, useMask);
        else
            convu_kernel<1, 0, 9><<<grid, blk, 0, stream>>>(in, wpk, bs, fg, outp, Cout, H, W, inCst, outCst, useMask);
    };
    auto up2h = [&](const _Float16* in, _Float16* out, int Hin, int Win) {
        int total = 4 * (Hin * 2) * (Win * 2) * 32;
        up2h_kernel<<<dim3((total + THREADS - 1) / THREADS), dim3(THREADS), 0, stream>>>(
            in, out, Hin, Win);
    };

    // ---- zero-page + pack head weights (GEMM format, persistent) ----
    zerows_kernel<<<dim3(4), dim3(THREADS), 0, stream>>>(zpage);
    pack_whead_kernel<<<dim3(576), dim3(THREADS), 0, stream>>>(head_w0, wpH0, 256);
    for (int i = 0; i < 7; ++i)
        pack_whead_kernel<<<dim3(1152), dim3(THREADS), 0, stream>>>(
            head_w + (size_t)i * 2359296, wpH + (size_t)i * 2359296, 512);

    // ---- transpose FPN inputs to NHWC fp16 ----
    transp(p2, p2h, 256, 16384);
    transp(p3, p3h, 256, 4096);
    transp(p4, p4h, 256, 1024);
    transp(p5, p5h, 256, 256);

    // ---- p2 scale head -> Xc (fp32 NHWC-288), coords+zeropad ----
    packw(w_p2_0, wpScale, 256, 256);
    convu(p2h, wpScale, b_p2_0, Xc, 0, 1, 256, 128, 128, 256, 288, 0);
    coords2_kernel<<<dim3(256), dim3(THREADS), 0, stream>>>(rel, abs_, Xc);

    // ---- p3 -> t64sum (write) ----
    packw(w_p3_0, wpScale, 256, 256);
    convu(p3h, wpScale, b_p3_0, t64sum, 0, 1, 256, 64, 64, 256, 256, 0);

    // ---- p4 chain: conv32 -> up -> conv64 (add into t64sum) ----
    packw(w_p4_0, wpScale, 256, 256);
    convu(p4h, wpScale, b_p4_0, t32a, 0, 0, 256, 32, 32, 256, 256, 0);
    up2h(t32a, t64b, 32, 32);
    packw(w_p4_1, wpScale, 256, 256);
    convu(t64b, wpScale, b_p4_1, t64sum, 0, 2, 256, 64, 64, 256, 256, 0);

    // ---- p5 chain: conv16 -> up -> conv32 -> up -> conv64 (add) ----
    packw(w_p5_0, wpScale, 256, 256);
    convu(p5h, wpScale, b_p5_0, t16a, 0, 0, 256, 16, 16, 256, 256, 0);
    up2h(t16a, t32b, 16, 16);
    packw(w_p5_1, wpScale, 256, 256);
    convu(t32b, wpScale, b_p5_1, t32c, 0, 0, 256, 32, 32, 256, 256, 0);
    up2h(t32c, t64c, 32, 32);
    packw(w_p5_2, wpScale, 256, 256);
    convu(t64c, wpScale, b_p5_2, t64sum, 0, 2, 256, 64, 64, 256, 256, 0);

    // ---- single upsample-add of merged 64^2 sum into Xc ----
    up2add_kernel<<<dim3(8192), dim3(THREADS), 0, stream>>>(t64sum, Xc);

    // ---- comb conv (Xc fp32 NHWC-288 -> combOut fp16 NHWC-256), relu+mask ----
    packw(comb_w, wpScale, 260, 256);
    convu(Xc, wpScale, comb_b, combOut, 1, 0, 256, 128, 128, 288, 256, 1);

    // ---- head chain: 256^2-tile LDS-staged GEMM convs, batched ----
    gemm_head_kernel<256><<<dim3(512), dim3(512), 0, stream>>>(
        combOut, wpH0, head_b0, fg, pingA, (const _Float16*)zpage);
    {
        const _Float16* s = pingA;
        _Float16* d = pingB;
        for (int i = 0; i < 7; ++i) {
            gemm_head_kernel<512><<<dim3(512), dim3(512), 0, stream>>>(
                s, wpH + (size_t)i * 2359296, head_b + (size_t)i * 512, fg, d,
                (const _Float16*)zpage);
            _Float16* tmp = (_Float16*)s; s = d; d = tmp;
        }
    }

    // ---- predictor (reads pingB), batched ----
    predh_kernel<<<dim3(64, 3, 4), dim3(256), 0, stream>>>(pingB, pred_w, pred_b, (float*)d_out);
}